// Round 8
// baseline (204.435 us; speedup 1.0000x reference)
//
#include <hip/hip_runtime.h>
#include <hip/hip_bf16.h>
#include <math.h>

#define HIDDEN 256
#define NCLS 10

typedef __attribute__((ext_vector_type(8))) short short8;
typedef __attribute__((ext_vector_type(4))) float f32x4;

// ---- bf16 helpers (bit-level, RTNE) ---------------------------------------
static __device__ __forceinline__ float bf16lo(unsigned u) {
    return __uint_as_float(u << 16);
}
static __device__ __forceinline__ float bf16hi(unsigned u) {
    return __uint_as_float(u & 0xffff0000u);
}
static __device__ __forceinline__ unsigned short f2bf(float f) {
    unsigned x = __float_as_uint(f);
    x += 0x7fffu + ((x >> 16) & 1u);       // round-to-nearest-even
    return (unsigned short)(x >> 16);
}
static __device__ __forceinline__ unsigned pack2(float lo, float hi) {
    return (unsigned)f2bf(lo) | ((unsigned)f2bf(hi) << 16);
}

// ---------------------------------------------------------------------------
// Hidden-state layout: half-split [2][Mp][128ch] (2.5 MB per half -> L2-fits).
// ---------------------------------------------------------------------------

// ---------------------------------------------------------------------------
// Merged: in-degree count (blocks [0,nbCount)) + dtype prep (rest).
// Prep: x f32->bf16 (half-split layout), W1/W2/W3 -> MFMA B-fragments
//   frag id = (s*16 + t)*64 + lane ; elems j: W[32s + 8*(l>>4)+j][16t + (l&15)]
// ---------------------------------------------------------------------------
__global__ __launch_bounds__(256) void k_count_prep(const int* __restrict__ dst,
                                                    int* __restrict__ ecnt, int E,
                                                    const float* __restrict__ x,
                                                    unsigned* __restrict__ x16,
                                                    const float* __restrict__ W1,
                                                    const float* __restrict__ W2,
                                                    const float* __restrict__ W3,
                                                    short8* __restrict__ P1,
                                                    short8* __restrict__ P2,
                                                    short8* __restrict__ P3,
                                                    int n4, int nbCount, int nb_cvt,
                                                    int Mp) {
    const int b = blockIdx.x;
    if (b < nbCount) {
        int e = b * 256 + threadIdx.x;
        if (e < E) atomicAdd(&ecnt[dst[e]], 1);
    } else if (b < nbCount + nb_cvt) {
        int i = (b - nbCount) * 256 + threadIdx.x;     // uint2 idx over [N][64]
        if (i < n4) {
            float4 v = reinterpret_cast<const float4*>(x)[i];
            uint2 o;
            o.x = pack2(v.x, v.y);
            o.y = pack2(v.z, v.w);
            int row = i >> 6;          // node
            int c4  = i & 63;          // uint2 within row (4 ch each)
            int half = c4 >> 5;        // ch >= 128 ?
            size_t idx = (size_t)half * Mp * 32 + (size_t)row * 32 + (c4 & 31);
            reinterpret_cast<uint2*>(x16)[idx] = o;
        }
    } else {
        int pb = b - nbCount - nb_cvt;            // 0..95
        int which = pb >> 5;
        int id = (pb & 31) * 256 + threadIdx.x;   // 0..8191
        const float* W = (which == 0) ? W1 : (which == 1) ? W2 : W3;
        short8* P = (which == 0) ? P1 : (which == 1) ? P2 : P3;
        int l = id & 63;
        int tt = (id >> 6) & 15;
        int s = id >> 10;
        int col = tt * 16 + (l & 15);
        int k0 = s * 32 + (l >> 4) * 8;
        short8 v;
#pragma unroll
        for (int j = 0; j < 8; ++j)
            v[j] = (short)f2bf(W[(size_t)(k0 + j) * HIDDEN + col]);
        P[id] = v;
    }
}

// single-block scan; also emits cursor (=rowstart) and dinv
__global__ __launch_bounds__(1024) void k_scan(const int* __restrict__ ecnt,
                                               int* __restrict__ rowstart,
                                               int* __restrict__ cursor,
                                               float* __restrict__ dinv, int N, int E) {
    __shared__ int sums[1024];
    int t = threadIdx.x;
    const int CH = (N + 1023) / 1024;
    int base = t * CH;
    int local = 0;
    for (int i = 0; i < CH; ++i) {
        int idx = base + i;
        if (idx < N) local += ecnt[idx];
    }
    sums[t] = local;
    __syncthreads();
    for (int off = 1; off < 1024; off <<= 1) {
        int v = (t >= off) ? sums[t - off] : 0;
        __syncthreads();
        sums[t] += v;
        __syncthreads();
    }
    int run = (t == 0) ? 0 : sums[t - 1];
    for (int i = 0; i < CH; ++i) {
        int idx = base + i;
        if (idx < N) {
            rowstart[idx] = run;
            cursor[idx] = run;
            dinv[idx] = rsqrtf((float)(ecnt[idx] + 1));   // +1 self loop
            run += ecnt[idx];
        }
    }
    if (t == 0) rowstart[N] = E;
}

// ---------------------------------------------------------------------------
// GEMM body: C = A @ W, A/C in half-split layout [2][Mp][128].
// Wave w: rows bx*64 + 16w, cols by*64 (4 n-frags). K fully unrolled.
// k-permutation-safe: A and B fragments use the same k formula.
// ---------------------------------------------------------------------------
static __device__ __forceinline__ void gemm_body(const unsigned short* __restrict__ A,
                                                 const short8* __restrict__ P,
                                                 unsigned short* __restrict__ C,
                                                 int bx, int by, int tid, int Mp) {
    const int l = tid & 63;
    const int w = tid >> 6;
    const int g = l >> 4;
    const int r = l & 15;
    const int mwave = bx * 64 + w * 16;
    const int nb = by * 4;

    f32x4 acc[4] = {};
    const unsigned short* arow0 = A + (size_t)(mwave + r) * 128 + g * 8;
    const unsigned short* arow1 = arow0 + (size_t)Mp * 128;

#pragma unroll
    for (int s = 0; s < 8; ++s) {
        const unsigned short* ap = (s < 4) ? arow0 : arow1;
        short8 a = *reinterpret_cast<const short8*>(ap + (s & 3) * 32);
#pragma unroll
        for (int f = 0; f < 4; ++f) {
            short8 bfrag = P[(s * 16 + nb + f) * 64 + l];
            acc[f] = __builtin_amdgcn_mfma_f32_16x16x32_bf16(a, bfrag, acc[f], 0, 0, 0);
        }
    }
#pragma unroll
    for (int f = 0; f < 4; ++f) {
        int col = by * 64 + f * 16 + r;
        unsigned short* cb = C + (size_t)(col >> 7) * Mp * 128 + (col & 127);
#pragma unroll
        for (int q = 0; q < 4; ++q) {
            int row = mwave + g * 4 + q;
            cb[(size_t)row * 128] = f2bf(acc[f][q]);
        }
    }
}

__global__ __launch_bounds__(256) void k_gemm(const unsigned short* __restrict__ A,
                                              const short8* __restrict__ P,
                                              unsigned short* __restrict__ C, int Mp) {
    gemm_body(A, P, C, blockIdx.x, blockIdx.y, threadIdx.x, Mp);
}

// ---------------------------------------------------------------------------
// Merged: CSR fill (blocks [0,nbFill)) + layer-1 GEMM (rest).
// ---------------------------------------------------------------------------
__global__ __launch_bounds__(256) void k_fill_gemm1(const int* __restrict__ src,
                                                    const int* __restrict__ dst,
                                                    const float* __restrict__ dinv,
                                                    int* __restrict__ cursor,
                                                    uint2* __restrict__ csr, int E,
                                                    const unsigned short* __restrict__ A,
                                                    const short8* __restrict__ P,
                                                    unsigned short* __restrict__ C,
                                                    int nbFill, int Mp) {
    const int b = blockIdx.x;
    if (b < nbFill) {
        int e = b * 256 + threadIdx.x;
        if (e < E) {
            int d = dst[e];
            int s = src[e];
            int pos = atomicAdd(&cursor[d], 1);
            uint2 ent;
            ent.x = (unsigned)s;
            ent.y = __float_as_uint(dinv[s] * dinv[d]);
            csr[pos] = ent;
        }
    } else {
        int gb = b - nbFill;            // flattened as (bx<<2)|by
        gemm_body(A, P, C, gb >> 2, gb & 3, threadIdx.x, Mp);
    }
}

// ---------------------------------------------------------------------------
// Aggregation over half-split H: grid (N/4, 2), y = channel half (dispatch
// y-major -> each 2.5MB half is L2-resident during its phase).
// Wave = node; lane l owns one uint (2 ch). Copy-free 2-deep pipeline
// (2x-unrolled role swap). csr padded +16 for speculative descriptor loads.
// ---------------------------------------------------------------------------
__global__ __launch_bounds__(256) void k_agg(const unsigned* __restrict__ H,
                                             const uint2* __restrict__ csr,
                                             const int* __restrict__ rowstart,
                                             const float* __restrict__ dinv,
                                             const float* __restrict__ bias,
                                             unsigned* __restrict__ out, int N, int Mp) {
    const int n = blockIdx.x * 4 + (threadIdx.x >> 6);
    if (n >= N) return;
    const int p = blockIdx.y;
    const int l = threadIdx.x & 63;
    const unsigned* __restrict__ Hh = H + (size_t)p * Mp * 64;

    float ax, ay;
    {
        const float di = dinv[n];
        unsigned u = Hh[(size_t)n * 64 + l];
        ax = bf16lo(u) * (di * di);
        ay = bf16hi(u) * (di * di);
    }

    const int base = rowstart[n];
    const int e1   = rowstart[n + 1];
    const int nfull = (e1 - base) >> 3;
    const uint2* cp = csr + base;

    if (nfull > 0) {
        uint2 d1[8];
        unsigned r0[8], r1[8];
        float w0[8], w1[8];
        {
            uint2 d0[8];
#pragma unroll
            for (int j = 0; j < 8; ++j) d0[j] = cp[j];
#pragma unroll
            for (int j = 0; j < 8; ++j) {
                r0[j] = Hh[(size_t)d0[j].x * 64 + l];
                w0[j] = __uint_as_float(d0[j].y);
            }
#pragma unroll
            for (int j = 0; j < 8; ++j) d1[j] = cp[8 + j];
        }
        int it = 0;
        for (; it + 2 < nfull; it += 2) {
            // consume iter it (r0/w0); rows for it+1 from d1; descs it+2 -> d1
#pragma unroll
            for (int j = 0; j < 8; ++j) r1[j] = Hh[(size_t)d1[j].x * 64 + l];
#pragma unroll
            for (int j = 0; j < 8; ++j) w1[j] = __uint_as_float(d1[j].y);
#pragma unroll
            for (int j = 0; j < 8; ++j) d1[j] = cp[16 + j];
#pragma unroll
            for (int j = 0; j < 8; ++j) {
                ax = fmaf(bf16lo(r0[j]), w0[j], ax);
                ay = fmaf(bf16hi(r0[j]), w0[j], ay);
            }
            cp += 8;
            // consume iter it+1 (r1/w1); rows for it+2 from d1; descs it+3 -> d1
#pragma unroll
            for (int j = 0; j < 8; ++j) r0[j] = Hh[(size_t)d1[j].x * 64 + l];
#pragma unroll
            for (int j = 0; j < 8; ++j) w0[j] = __uint_as_float(d1[j].y);
#pragma unroll
            for (int j = 0; j < 8; ++j) d1[j] = cp[16 + j];
#pragma unroll
            for (int j = 0; j < 8; ++j) {
                ax = fmaf(bf16lo(r1[j]), w1[j], ax);
                ay = fmaf(bf16hi(r1[j]), w1[j], ay);
            }
            cp += 8;
        }
        if (nfull - it == 2) {
#pragma unroll
            for (int j = 0; j < 8; ++j) r1[j] = Hh[(size_t)d1[j].x * 64 + l];
#pragma unroll
            for (int j = 0; j < 8; ++j) w1[j] = __uint_as_float(d1[j].y);
#pragma unroll
            for (int j = 0; j < 8; ++j) {
                ax = fmaf(bf16lo(r0[j]), w0[j], ax);
                ay = fmaf(bf16hi(r0[j]), w0[j], ay);
            }
#pragma unroll
            for (int j = 0; j < 8; ++j) {
                ax = fmaf(bf16lo(r1[j]), w1[j], ax);
                ay = fmaf(bf16hi(r1[j]), w1[j], ay);
            }
        } else {
#pragma unroll
            for (int j = 0; j < 8; ++j) {
                ax = fmaf(bf16lo(r0[j]), w0[j], ax);
                ay = fmaf(bf16hi(r0[j]), w0[j], ay);
            }
        }
    }
    // tail (< 8 edges)
    for (int e = base + 8 * nfull; e < e1; ++e) {
        uint2 ed = csr[e];
        unsigned u = Hh[(size_t)ed.x * 64 + l];
        float w = __uint_as_float(ed.y);
        ax = fmaf(bf16lo(u), w, ax);
        ay = fmaf(bf16hi(u), w, ay);
    }

    const float2 bv = reinterpret_cast<const float2*>(bias)[p * 64 + l];
    out[(size_t)p * Mp * 64 + (size_t)n * 64 + l] =
        pack2(fmaxf(ax + bv.x, 0.f), fmaxf(ay + bv.y, 0.f));
}

// ---------------------------------------------------------------------------
// Pool stage 1: partial sums. Grid (G, 8 strides), block 128.
// ---------------------------------------------------------------------------
__device__ __forceinline__ int lower_bound_i(const int* a, int n, int val) {
    int lo = 0, hi = n;
    while (lo < hi) {
        int mid = (lo + hi) >> 1;
        if (a[mid] < val) lo = mid + 1; else hi = mid;
    }
    return lo;
}

__global__ __launch_bounds__(128) void k_pool_part(const unsigned* __restrict__ H,
                                                   const int* __restrict__ batch,
                                                   float* __restrict__ partial,
                                                   int N, int Mp) {
    const int g = blockIdx.x;
    const int s = blockIdx.y;
    const int p = threadIdx.x;                    // channel pair 0..127
    const unsigned* __restrict__ Hh = H + (size_t)(p >> 6) * Mp * 64;
    const int c = p & 63;
    const int lo = lower_bound_i(batch, N, g);
    const int hi = lower_bound_i(batch, N, g + 1);
    float sx = 0.f, sy = 0.f;
    for (int n = lo + s; n < hi; n += 8) {
        unsigned u = Hh[(size_t)n * 64 + c];
        sx += bf16lo(u);
        sy += bf16hi(u);
    }
    float2 v; v.x = sx; v.y = sy;
    reinterpret_cast<float2*>(partial)[(size_t)(g * 8 + s) * 128 + p] = v;
}

// ---------------------------------------------------------------------------
// Classifier (+ pool stage 2). partial rows are in pair-index order:
// pair p covers channels (p>>6)*128 + 2*(p&63) + {0,1}.
// ---------------------------------------------------------------------------
__global__ __launch_bounds__(256) void k_cls(const float* __restrict__ partial,
                                             const int* __restrict__ batch,
                                             const float* __restrict__ Wlin,
                                             const float* __restrict__ blin,
                                             float* __restrict__ out, int N) {
    __shared__ float part[NCLS][HIDDEN];
    const int g = blockIdx.x;
    const int t = threadIdx.x;                    // flat slot 0..255 (pair p=t>>1, elem t&1)
    const int ch = ((t >> 1) >> 6) * 128 + 2 * ((t >> 1) & 63) + (t & 1);
    const int lo = lower_bound_i(batch, N, g);
    const int hi = lower_bound_i(batch, N, g + 1);
    float p = 0.f;
#pragma unroll
    for (int s = 0; s < 8; ++s) p += partial[(size_t)(g * 8 + s) * HIDDEN + t];
    p /= fmaxf((float)(hi - lo), 1.f);
#pragma unroll
    for (int c = 0; c < NCLS; ++c) part[c][t] = p * Wlin[(size_t)ch * NCLS + c];
    __syncthreads();
    for (int off = 128; off >= 1; off >>= 1) {
        if (t < off) {
#pragma unroll
            for (int c = 0; c < NCLS; ++c) part[c][t] += part[c][t + off];
        }
        __syncthreads();
    }
    if (t == 0) {
        float lg[NCLS];
        float m = -INFINITY;
#pragma unroll
        for (int c = 0; c < NCLS; ++c) {
            lg[c] = part[c][0] + blin[c];
            m = fmaxf(m, lg[c]);
        }
        float se = 0.f;
#pragma unroll
        for (int c = 0; c < NCLS; ++c) se += expf(lg[c] - m);
        float lse = m + logf(se);
#pragma unroll
        for (int c = 0; c < NCLS; ++c) out[(size_t)g * NCLS + c] = lg[c] - lse;
    }
}

// ---------------------------------------------------------------------------

extern "C" void kernel_launch(void* const* d_in, const int* in_sizes, int n_in,
                              void* d_out, int out_size, void* d_ws, size_t ws_size,
                              hipStream_t stream) {
    const float* x    = (const float*)d_in[0];
    const float* W1   = (const float*)d_in[1];
    const float* b1   = (const float*)d_in[2];
    const float* W2   = (const float*)d_in[3];
    const float* b2   = (const float*)d_in[4];
    const float* W3   = (const float*)d_in[5];
    const float* b3   = (const float*)d_in[6];
    const float* Wlin = (const float*)d_in[7];
    const float* blin = (const float*)d_in[8];
    const int*   eidx = (const int*)d_in[9];
    const int*   batch= (const int*)d_in[10];
    float* out = (float*)d_out;

    const int N = in_sizes[0] / HIDDEN;      // 10000
    const int E = in_sizes[9] / 2;           // 320000
    const int G = out_size / NCLS;           // 64
    const int Mp = (N + 63) & ~63;           // 10048

    const int* src = eidx;
    const int* dst = eidx + E;

    char* base = (char*)d_ws;
    size_t off = 0;
    auto alloc = [&](size_t bytes) -> void* {
        void* p = base + off;
        off = (off + bytes + 255) & ~(size_t)255;
        return p;
    };
    int*      ecnt     = (int*)     alloc((size_t)N * sizeof(int));
    int*      cursor   = (int*)     alloc((size_t)N * sizeof(int));
    float*    dinv     = (float*)   alloc((size_t)N * sizeof(float));
    int*      rowstart = (int*)     alloc((size_t)(N + 1) * sizeof(int));
    uint2*    csr      = (uint2*)   alloc((size_t)(E + 16) * sizeof(uint2)); // +16 pad (speculative desc loads)
    unsigned* x16      = (unsigned*)alloc((size_t)Mp * 128 * sizeof(unsigned));
    unsigned* hA       = (unsigned*)alloc((size_t)Mp * 128 * sizeof(unsigned));
    unsigned* hB       = (unsigned*)alloc((size_t)Mp * 128 * sizeof(unsigned));
    short8*   Wp1      = (short8*)  alloc((size_t)8192 * sizeof(short8));
    short8*   Wp2      = (short8*)  alloc((size_t)8192 * sizeof(short8));
    short8*   Wp3      = (short8*)  alloc((size_t)8192 * sizeof(short8));
    float*    partial  = (float*)   alloc((size_t)G * 8 * HIDDEN * sizeof(float));
    (void)ws_size;

    // --- preprocessing ---
    const int nbCount = (E + 255) / 256;          // 1250
    const int n4 = N * HIDDEN / 4;
    const int nb_cvt = (n4 + 255) / 256;          // 2500
    hipMemsetAsync(ecnt, 0, (size_t)N * sizeof(int), stream);
    k_count_prep<<<nbCount + nb_cvt + 96, 256, 0, stream>>>(
        dst, ecnt, E, x, x16, W1, W2, W3, Wp1, Wp2, Wp3, n4, nbCount, nb_cvt, Mp);
    k_scan<<<1, 1024, 0, stream>>>(ecnt, rowstart, cursor, dinv, N, E);

    // --- CSR fill + layer-1 GEMM (merged) ---
    const int nbFill = (E + 255) / 256;           // 1250
    const int gemmBlocks = (Mp / 64) * 4;         // 628
    k_fill_gemm1<<<nbFill + gemmBlocks, 256, 0, stream>>>(
        src, dst, dinv, cursor, csr, E,
        (const unsigned short*)x16, Wp1, (unsigned short*)hA, nbFill, Mp);

    const dim3 ggrid(Mp / 64, 4);
    const dim3 agrid((N + 3) / 4, 2);
    // --- layer 1 agg ---
    k_agg <<<agrid, 256, 0, stream>>>(hA, csr, rowstart, dinv, b1, hB, N, Mp);
    // --- layer 2 ---
    k_gemm<<<ggrid, 256, 0, stream>>>((const unsigned short*)hB, Wp2, (unsigned short*)hA, Mp);
    k_agg <<<agrid, 256, 0, stream>>>(hA, csr, rowstart, dinv, b2, hB, N, Mp);
    // --- layer 3 ---
    k_gemm<<<ggrid, 256, 0, stream>>>((const unsigned short*)hB, Wp3, (unsigned short*)hA, Mp);
    k_agg <<<agrid, 256, 0, stream>>>(hA, csr, rowstart, dinv, b3, hB, N, Mp);
    // --- pool (2-stage, deterministic) + classifier ---
    k_pool_part<<<dim3(G, 8), 128, 0, stream>>>(hB, batch, partial, N, Mp);
    k_cls <<<G, 256, 0, stream>>>(partial, batch, Wlin, blin, out, N);
}

// Round 10
// 193.284 us; speedup vs baseline: 1.0577x; 1.0577x over previous
//
#include <hip/hip_runtime.h>
#include <hip/hip_bf16.h>
#include <math.h>

#define HIDDEN 256
#define NCLS 10

typedef __attribute__((ext_vector_type(8))) short short8;
typedef __attribute__((ext_vector_type(4))) float f32x4;
typedef __attribute__((ext_vector_type(4))) unsigned u32x4;

// ---- bf16 helpers (bit-level, RTNE) ---------------------------------------
static __device__ __forceinline__ float bf16lo(unsigned u) {
    return __uint_as_float(u << 16);
}
static __device__ __forceinline__ float bf16hi(unsigned u) {
    return __uint_as_float(u & 0xffff0000u);
}
static __device__ __forceinline__ unsigned short f2bf(float f) {
    unsigned x = __float_as_uint(f);
    x += 0x7fffu + ((x >> 16) & 1u);       // round-to-nearest-even
    return (unsigned short)(x >> 16);
}
static __device__ __forceinline__ unsigned pack2(float lo, float hi) {
    return (unsigned)f2bf(lo) | ((unsigned)f2bf(hi) << 16);
}

static __device__ __forceinline__ void fma8(float* acc, uint4 u, float w) {
    acc[0] = fmaf(bf16lo(u.x), w, acc[0]);
    acc[1] = fmaf(bf16hi(u.x), w, acc[1]);
    acc[2] = fmaf(bf16lo(u.y), w, acc[2]);
    acc[3] = fmaf(bf16hi(u.y), w, acc[3]);
    acc[4] = fmaf(bf16lo(u.z), w, acc[4]);
    acc[5] = fmaf(bf16hi(u.z), w, acc[5]);
    acc[6] = fmaf(bf16lo(u.w), w, acc[6]);
    acc[7] = fmaf(bf16hi(u.w), w, acc[7]);
}

// ---------------------------------------------------------------------------
// Merged: in-degree count (blocks [0,nbCount)) + dtype prep (rest).
// Prep: x f32->bf16 (flat [Mp][256]), W1/W2/W3 -> MFMA B-fragments
//   frag id = (s*16 + t)*64 + lane ; elems j: W[32s + 8*(l>>4)+j][16t + (l&15)]
// ---------------------------------------------------------------------------
__global__ __launch_bounds__(256) void k_count_prep(const int* __restrict__ dst,
                                                    int* __restrict__ ecnt, int E,
                                                    const float* __restrict__ x,
                                                    unsigned* __restrict__ x16,
                                                    const float* __restrict__ W1,
                                                    const float* __restrict__ W2,
                                                    const float* __restrict__ W3,
                                                    short8* __restrict__ P1,
                                                    short8* __restrict__ P2,
                                                    short8* __restrict__ P3,
                                                    int n4, int nbCount, int nb_cvt) {
    const int b = blockIdx.x;
    if (b < nbCount) {
        int e = b * 256 + threadIdx.x;
        if (e < E) atomicAdd(&ecnt[dst[e]], 1);
    } else if (b < nbCount + nb_cvt) {
        int i = (b - nbCount) * 256 + threadIdx.x;
        if (i < n4) {
            float4 v = reinterpret_cast<const float4*>(x)[i];
            uint2 o;
            o.x = pack2(v.x, v.y);
            o.y = pack2(v.z, v.w);
            reinterpret_cast<uint2*>(x16)[i] = o;
        }
    } else {
        int pb = b - nbCount - nb_cvt;            // 0..95
        int which = pb >> 5;
        int id = (pb & 31) * 256 + threadIdx.x;   // 0..8191
        const float* W = (which == 0) ? W1 : (which == 1) ? W2 : W3;
        short8* P = (which == 0) ? P1 : (which == 1) ? P2 : P3;
        int l = id & 63;
        int tt = (id >> 6) & 15;
        int s = id >> 10;
        int col = tt * 16 + (l & 15);
        int k0 = s * 32 + (l >> 4) * 8;
        short8 v;
#pragma unroll
        for (int j = 0; j < 8; ++j)
            v[j] = (short)f2bf(W[(size_t)(k0 + j) * HIDDEN + col]);
        P[id] = v;
    }
}

// single-block scan; also emits cursor (=rowstart) and dinv
__global__ __launch_bounds__(1024) void k_scan(const int* __restrict__ ecnt,
                                               int* __restrict__ rowstart,
                                               int* __restrict__ cursor,
                                               float* __restrict__ dinv, int N, int E) {
    __shared__ int sums[1024];
    int t = threadIdx.x;
    const int CH = (N + 1023) / 1024;
    int base = t * CH;
    int local = 0;
    for (int i = 0; i < CH; ++i) {
        int idx = base + i;
        if (idx < N) local += ecnt[idx];
    }
    sums[t] = local;
    __syncthreads();
    for (int off = 1; off < 1024; off <<= 1) {
        int v = (t >= off) ? sums[t - off] : 0;
        __syncthreads();
        sums[t] += v;
        __syncthreads();
    }
    int run = (t == 0) ? 0 : sums[t - 1];
    for (int i = 0; i < CH; ++i) {
        int idx = base + i;
        if (idx < N) {
            rowstart[idx] = run;
            cursor[idx] = run;
            dinv[idx] = rsqrtf((float)(ecnt[idx] + 1));   // +1 self loop
            run += ecnt[idx];
        }
    }
    if (t == 0) rowstart[N] = E;
}

// ---------------------------------------------------------------------------
// GEMM body: C[Mp,256] = A[Mp,256] @ W (pre-packed fragments).
// Wave w: rows bx*64 + 16w, cols by*64 (4 n-frags). K fully unrolled.
// ---------------------------------------------------------------------------
static __device__ __forceinline__ void gemm_body(const unsigned short* __restrict__ A,
                                                 const short8* __restrict__ P,
                                                 unsigned short* __restrict__ C,
                                                 int bx, int by, int tid) {
    const int l = tid & 63;
    const int w = tid >> 6;
    const int g = l >> 4;
    const int r = l & 15;
    const int mwave = bx * 64 + w * 16;
    const int nb = by * 4;

    f32x4 acc[4] = {};
    const unsigned short* arow = A + (size_t)(mwave + r) * HIDDEN;

#pragma unroll
    for (int s = 0; s < 8; ++s) {
        short8 a = *reinterpret_cast<const short8*>(arow + s * 32 + g * 8);
#pragma unroll
        for (int f = 0; f < 4; ++f) {
            short8 bfrag = P[(s * 16 + nb + f) * 64 + l];
            acc[f] = __builtin_amdgcn_mfma_f32_16x16x32_bf16(a, bfrag, acc[f], 0, 0, 0);
        }
    }
#pragma unroll
    for (int f = 0; f < 4; ++f) {
        int col = by * 64 + f * 16 + r;
#pragma unroll
        for (int q = 0; q < 4; ++q) {
            int row = mwave + g * 4 + q;
            C[(size_t)row * HIDDEN + col] = f2bf(acc[f][q]);
        }
    }
}

__global__ __launch_bounds__(256) void k_gemm(const unsigned short* __restrict__ A,
                                              const short8* __restrict__ P,
                                              unsigned short* __restrict__ C) {
    gemm_body(A, P, C, blockIdx.x, blockIdx.y, threadIdx.x);
}

// ---------------------------------------------------------------------------
// Merged: CSR fill (blocks [0,nbFill)) + layer-1 GEMM (rest).
// ---------------------------------------------------------------------------
__global__ __launch_bounds__(256) void k_fill_gemm1(const int* __restrict__ src,
                                                    const int* __restrict__ dst,
                                                    const float* __restrict__ dinv,
                                                    int* __restrict__ cursor,
                                                    uint2* __restrict__ csr, int E,
                                                    const unsigned short* __restrict__ A,
                                                    const short8* __restrict__ P,
                                                    unsigned short* __restrict__ C,
                                                    int nbFill) {
    const int b = blockIdx.x;
    if (b < nbFill) {
        int e = b * 256 + threadIdx.x;
        if (e < E) {
            int d = dst[e];
            int s = src[e];
            int pos = atomicAdd(&cursor[d], 1);
            uint2 ent;
            ent.x = (unsigned)s;
            ent.y = __float_as_uint(dinv[s] * dinv[d]);
            csr[pos] = ent;
        }
    } else {
        int gb = b - nbFill;            // flattened as (bx<<2)|by
        gemm_body(A, P, C, gb >> 2, gb & 3, threadIdx.x);
    }
}

// ---------------------------------------------------------------------------
// Aggregation, channel-half phased: grid (N/4, 2), y = half (x-fastest
// dispatch -> all y=0 blocks run first; their 2.5MB line working set fits
// per-XCD L2 even in the flat [Mp][256] layout — caches are line-granular).
// Wave = node. Lane: quarter qa=l>>4 = edge substream (4 concurrent),
// chunk c=l&15 = 16B of the 256B half-row. 16 edges/iter, 2-deep pipeline.
// csr reads non-temporal (streaming); out store non-temporal (u32x4).
// csr padded +32 entries for speculative descriptor loads.
// ---------------------------------------------------------------------------
__global__ __launch_bounds__(256) void k_agg(const unsigned* __restrict__ H,
                                             const uint2* __restrict__ csr,
                                             const int* __restrict__ rowstart,
                                             const float* __restrict__ dinv,
                                             const float* __restrict__ bias,
                                             unsigned* __restrict__ out, int N) {
    const int n = blockIdx.x * 4 + (threadIdx.x >> 6);
    if (n >= N) return;
    const int p = blockIdx.y;
    const int l = threadIdx.x & 63;
    const int qa = l >> 4;                 // edge substream 0..3
    const int c  = l & 15;                 // 16B chunk within half-row
    const int hoff = p * 16 + c;           // uint4 offset within row
    const uint4* __restrict__ H4 = reinterpret_cast<const uint4*>(H);

    float acc[8] = {0.f, 0.f, 0.f, 0.f, 0.f, 0.f, 0.f, 0.f};
    if (qa == 0) {
        const float di = dinv[n];
        fma8(acc, H4[(size_t)n * 32 + hoff], di * di);
    }

    const int base = rowstart[n];
    const int e1   = rowstart[n + 1];
    const int nfull = (e1 - base) >> 4;    // iterations of 16 edges
    const unsigned long long* cp =
        reinterpret_cast<const unsigned long long*>(csr) + base + qa * 4;

    if (nfull > 0) {
        unsigned long long dA[4], dB[4];
        uint4 rA[4];
#pragma unroll
        for (int j = 0; j < 4; ++j) dA[j] = __builtin_nontemporal_load(cp + j);
#pragma unroll
        for (int j = 0; j < 4; ++j) rA[j] = H4[(size_t)(unsigned)dA[j] * 32 + hoff];
#pragma unroll
        for (int j = 0; j < 4; ++j) dB[j] = __builtin_nontemporal_load(cp + 16 + j);

        for (int it = 0; it + 1 < nfull; ++it) {
            cp += 16;
            uint4 rB[4];
#pragma unroll
            for (int j = 0; j < 4; ++j) rB[j] = H4[(size_t)(unsigned)dB[j] * 32 + hoff];
            unsigned long long dC[4];
#pragma unroll
            for (int j = 0; j < 4; ++j) dC[j] = __builtin_nontemporal_load(cp + 16 + j);
#pragma unroll
            for (int j = 0; j < 4; ++j)
                fma8(acc, rA[j], __uint_as_float((unsigned)(dA[j] >> 32)));
#pragma unroll
            for (int j = 0; j < 4; ++j) { dA[j] = dB[j]; dB[j] = dC[j]; rA[j] = rB[j]; }
        }
#pragma unroll
        for (int j = 0; j < 4; ++j)
            fma8(acc, rA[j], __uint_as_float((unsigned)(dA[j] >> 32)));
    }
    // tail (< 16 edges): quarters take every 4th
    for (int e = base + 16 * nfull + qa; e < e1; e += 4) {
        uint2 ed = csr[e];
        fma8(acc, H4[(size_t)ed.x * 32 + hoff], __uint_as_float(ed.y));
    }

    // cross-quarter reduce
#pragma unroll
    for (int j = 0; j < 8; ++j) {
        acc[j] += __shfl_xor(acc[j], 16);
        acc[j] += __shfl_xor(acc[j], 32);
    }

    if (qa == 0) {
        const float4* __restrict__ b4 = reinterpret_cast<const float4*>(bias);
        float4 ba = b4[hoff * 2];
        float4 bb = b4[hoff * 2 + 1];
        u32x4 o;
        o.x = pack2(fmaxf(acc[0] + ba.x, 0.f), fmaxf(acc[1] + ba.y, 0.f));
        o.y = pack2(fmaxf(acc[2] + ba.z, 0.f), fmaxf(acc[3] + ba.w, 0.f));
        o.z = pack2(fmaxf(acc[4] + bb.x, 0.f), fmaxf(acc[5] + bb.y, 0.f));
        o.w = pack2(fmaxf(acc[6] + bb.z, 0.f), fmaxf(acc[7] + bb.w, 0.f));
        __builtin_nontemporal_store(o, reinterpret_cast<u32x4*>(out) + (size_t)n * 32 + hoff);
    }
}

// ---------------------------------------------------------------------------
// Pool stage 1: partial sums. Grid (G, 8 strides), block 128.
// ---------------------------------------------------------------------------
__device__ __forceinline__ int lower_bound_i(const int* a, int n, int val) {
    int lo = 0, hi = n;
    while (lo < hi) {
        int mid = (lo + hi) >> 1;
        if (a[mid] < val) lo = mid + 1; else hi = mid;
    }
    return lo;
}

__global__ __launch_bounds__(128) void k_pool_part(const unsigned* __restrict__ H,
                                                   const int* __restrict__ batch,
                                                   float* __restrict__ partial, int N) {
    const int g = blockIdx.x;
    const int s = blockIdx.y;
    const int p = threadIdx.x;
    const int lo = lower_bound_i(batch, N, g);
    const int hi = lower_bound_i(batch, N, g + 1);
    float sx = 0.f, sy = 0.f;
    for (int n = lo + s; n < hi; n += 8) {
        unsigned u = H[(size_t)n * 128 + p];
        sx += bf16lo(u);
        sy += bf16hi(u);
    }
    float2 v; v.x = sx; v.y = sy;
    reinterpret_cast<float2*>(partial)[(size_t)(g * 8 + s) * 128 + p] = v;
}

// ---------------------------------------------------------------------------
// Classifier (+ pool stage 2)
// ---------------------------------------------------------------------------
__global__ __launch_bounds__(256) void k_cls(const float* __restrict__ partial,
                                             const int* __restrict__ batch,
                                             const float* __restrict__ Wlin,
                                             const float* __restrict__ blin,
                                             float* __restrict__ out, int N) {
    __shared__ float part[NCLS][HIDDEN];
    const int g = blockIdx.x;
    const int t = threadIdx.x;
    const int lo = lower_bound_i(batch, N, g);
    const int hi = lower_bound_i(batch, N, g + 1);
    float p = 0.f;
#pragma unroll
    for (int s = 0; s < 8; ++s) p += partial[(size_t)(g * 8 + s) * HIDDEN + t];
    p /= fmaxf((float)(hi - lo), 1.f);
#pragma unroll
    for (int c = 0; c < NCLS; ++c) part[c][t] = p * Wlin[(size_t)t * NCLS + c];
    __syncthreads();
    for (int off = 128; off >= 1; off >>= 1) {
        if (t < off) {
#pragma unroll
            for (int c = 0; c < NCLS; ++c) part[c][t] += part[c][t + off];
        }
        __syncthreads();
    }
    if (t == 0) {
        float lg[NCLS];
        float m = -INFINITY;
#pragma unroll
        for (int c = 0; c < NCLS; ++c) {
            lg[c] = part[c][0] + blin[c];
            m = fmaxf(m, lg[c]);
        }
        float se = 0.f;
#pragma unroll
        for (int c = 0; c < NCLS; ++c) se += expf(lg[c] - m);
        float lse = m + logf(se);
#pragma unroll
        for (int c = 0; c < NCLS; ++c) out[(size_t)g * NCLS + c] = lg[c] - lse;
    }
}

// ---------------------------------------------------------------------------

extern "C" void kernel_launch(void* const* d_in, const int* in_sizes, int n_in,
                              void* d_out, int out_size, void* d_ws, size_t ws_size,
                              hipStream_t stream) {
    const float* x    = (const float*)d_in[0];
    const float* W1   = (const float*)d_in[1];
    const float* b1   = (const float*)d_in[2];
    const float* W2   = (const float*)d_in[3];
    const float* b2   = (const float*)d_in[4];
    const float* W3   = (const float*)d_in[5];
    const float* b3   = (const float*)d_in[6];
    const float* Wlin = (const float*)d_in[7];
    const float* blin = (const float*)d_in[8];
    const int*   eidx = (const int*)d_in[9];
    const int*   batch= (const int*)d_in[10];
    float* out = (float*)d_out;

    const int N = in_sizes[0] / HIDDEN;      // 10000
    const int E = in_sizes[9] / 2;           // 320000
    const int G = out_size / NCLS;           // 64
    const int Mp = (N + 63) & ~63;           // 10048

    const int* src = eidx;
    const int* dst = eidx + E;

    char* base = (char*)d_ws;
    size_t off = 0;
    auto alloc = [&](size_t bytes) -> void* {
        void* p = base + off;
        off = (off + bytes + 255) & ~(size_t)255;
        return p;
    };
    int*      ecnt     = (int*)     alloc((size_t)N * sizeof(int));
    int*      cursor   = (int*)     alloc((size_t)N * sizeof(int));
    float*    dinv     = (float*)   alloc((size_t)N * sizeof(float));
    int*      rowstart = (int*)     alloc((size_t)(N + 1) * sizeof(int));
    uint2*    csr      = (uint2*)   alloc((size_t)(E + 32) * sizeof(uint2)); // +32 pad (speculative desc loads)
    unsigned* x16      = (unsigned*)alloc((size_t)Mp * 128 * sizeof(unsigned));
    unsigned* hA       = (unsigned*)alloc((size_t)Mp * 128 * sizeof(unsigned));
    unsigned* hB       = (unsigned*)alloc((size_t)Mp * 128 * sizeof(unsigned));
    short8*   Wp1      = (short8*)  alloc((size_t)8192 * sizeof(short8));
    short8*   Wp2      = (short8*)  alloc((size_t)8192 * sizeof(short8));
    short8*   Wp3      = (short8*)  alloc((size_t)8192 * sizeof(short8));
    float*    partial  = (float*)   alloc((size_t)G * 8 * HIDDEN * sizeof(float));
    (void)ws_size;

    // --- preprocessing ---
    const int nbCount = (E + 255) / 256;          // 1250
    const int n4 = N * HIDDEN / 4;
    const int nb_cvt = (n4 + 255) / 256;          // 2500
    (void)hipMemsetAsync(ecnt, 0, (size_t)N * sizeof(int), stream);
    k_count_prep<<<nbCount + nb_cvt + 96, 256, 0, stream>>>(
        dst, ecnt, E, x, x16, W1, W2, W3, Wp1, Wp2, Wp3, n4, nbCount, nb_cvt);
    k_scan<<<1, 1024, 0, stream>>>(ecnt, rowstart, cursor, dinv, N, E);

    // --- CSR fill + layer-1 GEMM (merged) ---
    const int nbFill = (E + 255) / 256;           // 1250
    const int gemmBlocks = (Mp / 64) * 4;         // 628
    k_fill_gemm1<<<nbFill + gemmBlocks, 256, 0, stream>>>(
        src, dst, dinv, cursor, csr, E,
        (const unsigned short*)x16, Wp1, (unsigned short*)hA, nbFill);

    const dim3 ggrid(Mp / 64, 4);
    const dim3 agrid((N + 3) / 4, 2);
    // --- layer 1 agg ---
    k_agg <<<agrid, 256, 0, stream>>>(hA, csr, rowstart, dinv, b1, hB, N);
    // --- layer 2 ---
    k_gemm<<<ggrid, 256, 0, stream>>>((const unsigned short*)hB, Wp2, (unsigned short*)hA);
    k_agg <<<agrid, 256, 0, stream>>>(hA, csr, rowstart, dinv, b2, hB, N);
    // --- layer 3 ---
    k_gemm<<<ggrid, 256, 0, stream>>>((const unsigned short*)hB, Wp3, (unsigned short*)hA);
    k_agg <<<agrid, 256, 0, stream>>>(hA, csr, rowstart, dinv, b3, hB, N);
    // --- pool (2-stage, deterministic) + classifier ---
    k_pool_part<<<dim3(G, 8), 128, 0, stream>>>(hB, batch, partial, N);
    k_cls <<<G, 256, 0, stream>>>(partial, batch, Wlin, blin, out, N);
}

// Round 11
// 174.880 us; speedup vs baseline: 1.1690x; 1.1052x over previous
//
#include <hip/hip_runtime.h>
#include <hip/hip_bf16.h>
#include <math.h>

#define HIDDEN 256
#define NCLS 10

typedef __attribute__((ext_vector_type(8))) short short8;
typedef __attribute__((ext_vector_type(4))) float f32x4;

// ---- bf16 helpers (bit-level, RTNE) ---------------------------------------
static __device__ __forceinline__ float bf16lo(unsigned u) {
    return __uint_as_float(u << 16);
}
static __device__ __forceinline__ float bf16hi(unsigned u) {
    return __uint_as_float(u & 0xffff0000u);
}
static __device__ __forceinline__ unsigned short f2bf(float f) {
    unsigned x = __float_as_uint(f);
    x += 0x7fffu + ((x >> 16) & 1u);       // round-to-nearest-even
    return (unsigned short)(x >> 16);
}
static __device__ __forceinline__ unsigned pack2(float lo, float hi) {
    return (unsigned)f2bf(lo) | ((unsigned)f2bf(hi) << 16);
}

static __device__ __forceinline__ void fma8(float* acc, uint4 u, float w) {
    acc[0] = fmaf(bf16lo(u.x), w, acc[0]);
    acc[1] = fmaf(bf16hi(u.x), w, acc[1]);
    acc[2] = fmaf(bf16lo(u.y), w, acc[2]);
    acc[3] = fmaf(bf16hi(u.y), w, acc[3]);
    acc[4] = fmaf(bf16lo(u.z), w, acc[4]);
    acc[5] = fmaf(bf16hi(u.z), w, acc[5]);
    acc[6] = fmaf(bf16lo(u.w), w, acc[6]);
    acc[7] = fmaf(bf16hi(u.w), w, acc[7]);
}

// ---------------------------------------------------------------------------
// Zero init for degree counters. (hipMemsetAsync measured at ~42us/replay in
// the captured graph — blit fill pathology. A plain kernel is ~1.5us.)
// ---------------------------------------------------------------------------
__global__ void k_zero(int* __restrict__ ecnt, int N) {
    int i = blockIdx.x * blockDim.x + threadIdx.x;
    if (i < N) ecnt[i] = 0;
}

// ---------------------------------------------------------------------------
// Merged: in-degree count (blocks [0,nbCount)) + dtype prep (rest).
// Prep: x f32->bf16 (flat [Mp][256]), W1/W2/W3 -> MFMA B-fragments
//   frag id = (s*16 + t)*64 + lane ; elems j: W[32s + 8*(l>>4)+j][16t + (l&15)]
// ---------------------------------------------------------------------------
__global__ __launch_bounds__(256) void k_count_prep(const int* __restrict__ dst,
                                                    int* __restrict__ ecnt, int E,
                                                    const float* __restrict__ x,
                                                    unsigned* __restrict__ x16,
                                                    const float* __restrict__ W1,
                                                    const float* __restrict__ W2,
                                                    const float* __restrict__ W3,
                                                    short8* __restrict__ P1,
                                                    short8* __restrict__ P2,
                                                    short8* __restrict__ P3,
                                                    int n4, int nbCount, int nb_cvt) {
    const int b = blockIdx.x;
    if (b < nbCount) {
        int e = b * 256 + threadIdx.x;
        if (e < E) atomicAdd(&ecnt[dst[e]], 1);
    } else if (b < nbCount + nb_cvt) {
        int i = (b - nbCount) * 256 + threadIdx.x;
        if (i < n4) {
            float4 v = reinterpret_cast<const float4*>(x)[i];
            uint2 o;
            o.x = pack2(v.x, v.y);
            o.y = pack2(v.z, v.w);
            reinterpret_cast<uint2*>(x16)[i] = o;
        }
    } else {
        int pb = b - nbCount - nb_cvt;            // 0..95
        int which = pb >> 5;
        int id = (pb & 31) * 256 + threadIdx.x;   // 0..8191
        const float* W = (which == 0) ? W1 : (which == 1) ? W2 : W3;
        short8* P = (which == 0) ? P1 : (which == 1) ? P2 : P3;
        int l = id & 63;
        int tt = (id >> 6) & 15;
        int s = id >> 10;
        int col = tt * 16 + (l & 15);
        int k0 = s * 32 + (l >> 4) * 8;
        short8 v;
#pragma unroll
        for (int j = 0; j < 8; ++j)
            v[j] = (short)f2bf(W[(size_t)(k0 + j) * HIDDEN + col]);
        P[id] = v;
    }
}

// single-block scan; also emits cursor (=rowstart) and dinv
__global__ __launch_bounds__(1024) void k_scan(const int* __restrict__ ecnt,
                                               int* __restrict__ rowstart,
                                               int* __restrict__ cursor,
                                               float* __restrict__ dinv, int N, int E) {
    __shared__ int sums[1024];
    int t = threadIdx.x;
    const int CH = (N + 1023) / 1024;
    int base = t * CH;
    int local = 0;
    for (int i = 0; i < CH; ++i) {
        int idx = base + i;
        if (idx < N) local += ecnt[idx];
    }
    sums[t] = local;
    __syncthreads();
    for (int off = 1; off < 1024; off <<= 1) {
        int v = (t >= off) ? sums[t - off] : 0;
        __syncthreads();
        sums[t] += v;
        __syncthreads();
    }
    int run = (t == 0) ? 0 : sums[t - 1];
    for (int i = 0; i < CH; ++i) {
        int idx = base + i;
        if (idx < N) {
            rowstart[idx] = run;
            cursor[idx] = run;
            dinv[idx] = rsqrtf((float)(ecnt[idx] + 1));   // +1 self loop
            run += ecnt[idx];
        }
    }
    if (t == 0) rowstart[N] = E;
}

// ---------------------------------------------------------------------------
// GEMM body: C[Mp,256] = A[Mp,256] @ W (pre-packed fragments).
// Wave w: rows bx*64 + 16w, cols by*64 (4 n-frags). K fully unrolled.
// ---------------------------------------------------------------------------
static __device__ __forceinline__ void gemm_body(const unsigned short* __restrict__ A,
                                                 const short8* __restrict__ P,
                                                 unsigned short* __restrict__ C,
                                                 int bx, int by, int tid) {
    const int l = tid & 63;
    const int w = tid >> 6;
    const int g = l >> 4;
    const int r = l & 15;
    const int mwave = bx * 64 + w * 16;
    const int nb = by * 4;

    f32x4 acc[4] = {};
    const unsigned short* arow = A + (size_t)(mwave + r) * HIDDEN;

#pragma unroll
    for (int s = 0; s < 8; ++s) {
        short8 a = *reinterpret_cast<const short8*>(arow + s * 32 + g * 8);
#pragma unroll
        for (int f = 0; f < 4; ++f) {
            short8 bfrag = P[(s * 16 + nb + f) * 64 + l];
            acc[f] = __builtin_amdgcn_mfma_f32_16x16x32_bf16(a, bfrag, acc[f], 0, 0, 0);
        }
    }
#pragma unroll
    for (int f = 0; f < 4; ++f) {
        int col = by * 64 + f * 16 + r;
#pragma unroll
        for (int q = 0; q < 4; ++q) {
            int row = mwave + g * 4 + q;
            C[(size_t)row * HIDDEN + col] = f2bf(acc[f][q]);
        }
    }
}

__global__ __launch_bounds__(256) void k_gemm(const unsigned short* __restrict__ A,
                                              const short8* __restrict__ P,
                                              unsigned short* __restrict__ C) {
    gemm_body(A, P, C, blockIdx.x, blockIdx.y, threadIdx.x);
}

// ---------------------------------------------------------------------------
// Merged: CSR fill (blocks [0,nbFill)) + layer-1 GEMM (rest).
// ---------------------------------------------------------------------------
__global__ __launch_bounds__(256) void k_fill_gemm1(const int* __restrict__ src,
                                                    const int* __restrict__ dst,
                                                    const float* __restrict__ dinv,
                                                    int* __restrict__ cursor,
                                                    uint2* __restrict__ csr, int E,
                                                    const unsigned short* __restrict__ A,
                                                    const short8* __restrict__ P,
                                                    unsigned short* __restrict__ C,
                                                    int nbFill) {
    const int b = blockIdx.x;
    if (b < nbFill) {
        int e = b * 256 + threadIdx.x;
        if (e < E) {
            int d = dst[e];
            int s = src[e];
            int pos = atomicAdd(&cursor[d], 1);
            uint2 ent;
            ent.x = (unsigned)s;
            ent.y = __float_as_uint(dinv[s] * dinv[d]);
            csr[pos] = ent;
        }
    } else {
        int gb = b - nbFill;            // flattened as (bx<<2)|by
        gemm_body(A, P, C, gb >> 2, gb & 3, threadIdx.x);
    }
}

// ---------------------------------------------------------------------------
// Aggregation (bf16 H): out[n] = relu( sum_e H[src]*w + H[n]*dinv^2 + b )
// Block = 4 waves = 4 nodes. Lane: chunk q=l&31 (8 ch, uint4), half h=l>>5.
// 2-stage software pipeline: while fma-ing iter i, iter i+1's row gathers and
// iter i+2's descriptors are in flight. Descriptors are stream-once data ->
// non-temporal 64-bit loads (protect H's L2 lines). csr padded +32 so
// speculative descriptor loads are safe (never dereferenced past row end).
// ---------------------------------------------------------------------------
__global__ __launch_bounds__(256) void k_agg(const unsigned* __restrict__ H,
                                             const uint2* __restrict__ csr,
                                             const int* __restrict__ rowstart,
                                             const float* __restrict__ dinv,
                                             const float* __restrict__ bias,
                                             unsigned* __restrict__ out, int N) {
    const int n = blockIdx.x * 4 + (threadIdx.x >> 6);
    if (n >= N) return;
    const int l = threadIdx.x & 63;
    const int q = l & 31;
    const int h = l >> 5;
    const uint4* __restrict__ H4 = reinterpret_cast<const uint4*>(H);

    float acc[8] = {0.f, 0.f, 0.f, 0.f, 0.f, 0.f, 0.f, 0.f};
    if (h == 0) {
        const float di = dinv[n];
        fma8(acc, H4[(size_t)n * 32 + q], di * di);
    }

    const int base = rowstart[n];
    const int e1   = rowstart[n + 1];
    const int nfull = (e1 - base) >> 3;          // iterations of 8 edges
    const unsigned long long* cp =
        reinterpret_cast<const unsigned long long*>(csr) + base + 4 * h;  // this half's stream

    if (nfull > 0) {
        // prologue: iter0 descriptors + rows, iter1 descriptors
        unsigned long long dA0 = __builtin_nontemporal_load(cp + 0);
        unsigned long long dA1 = __builtin_nontemporal_load(cp + 1);
        unsigned long long dA2 = __builtin_nontemporal_load(cp + 2);
        unsigned long long dA3 = __builtin_nontemporal_load(cp + 3);
        uint4 rA0 = H4[(size_t)(unsigned)dA0 * 32 + q];
        uint4 rA1 = H4[(size_t)(unsigned)dA1 * 32 + q];
        uint4 rA2 = H4[(size_t)(unsigned)dA2 * 32 + q];
        uint4 rA3 = H4[(size_t)(unsigned)dA3 * 32 + q];
        unsigned long long dB0 = __builtin_nontemporal_load(cp + 8);
        unsigned long long dB1 = __builtin_nontemporal_load(cp + 9);
        unsigned long long dB2 = __builtin_nontemporal_load(cp + 10);
        unsigned long long dB3 = __builtin_nontemporal_load(cp + 11);
        for (int it = 0; it + 1 < nfull; ++it) {
            cp += 8;
            uint4 rB0 = H4[(size_t)(unsigned)dB0 * 32 + q];   // rows for iter it+1
            uint4 rB1 = H4[(size_t)(unsigned)dB1 * 32 + q];
            uint4 rB2 = H4[(size_t)(unsigned)dB2 * 32 + q];
            uint4 rB3 = H4[(size_t)(unsigned)dB3 * 32 + q];
            unsigned long long dC0 = __builtin_nontemporal_load(cp + 8);   // descs iter it+2
            unsigned long long dC1 = __builtin_nontemporal_load(cp + 9);
            unsigned long long dC2 = __builtin_nontemporal_load(cp + 10);
            unsigned long long dC3 = __builtin_nontemporal_load(cp + 11);
            fma8(acc, rA0, __uint_as_float((unsigned)(dA0 >> 32)));        // consume iter it
            fma8(acc, rA1, __uint_as_float((unsigned)(dA1 >> 32)));
            fma8(acc, rA2, __uint_as_float((unsigned)(dA2 >> 32)));
            fma8(acc, rA3, __uint_as_float((unsigned)(dA3 >> 32)));
            dA0 = dB0; dA1 = dB1; dA2 = dB2; dA3 = dB3;
            dB0 = dC0; dB1 = dC1; dB2 = dC2; dB3 = dC3;
            rA0 = rB0; rA1 = rB1; rA2 = rB2; rA3 = rB3;
        }
        fma8(acc, rA0, __uint_as_float((unsigned)(dA0 >> 32)));            // last full iter
        fma8(acc, rA1, __uint_as_float((unsigned)(dA1 >> 32)));
        fma8(acc, rA2, __uint_as_float((unsigned)(dA2 >> 32)));
        fma8(acc, rA3, __uint_as_float((unsigned)(dA3 >> 32)));
    }
    // tail: < 8 remaining edges, split by half (stride 2)
    for (int e = base + 8 * nfull + h; e < e1; e += 2) {
        uint2 ed = csr[e];
        fma8(acc, H4[(size_t)ed.x * 32 + q], __uint_as_float(ed.y));
    }

#pragma unroll
    for (int j = 0; j < 8; ++j) acc[j] += __shfl_xor(acc[j], 32);

    if (h == 0) {
        const float4* __restrict__ b4 = reinterpret_cast<const float4*>(bias);
        float4 ba = b4[q * 2];
        float4 bb = b4[q * 2 + 1];
        uint4 o;
        o.x = pack2(fmaxf(acc[0] + ba.x, 0.f), fmaxf(acc[1] + ba.y, 0.f));
        o.y = pack2(fmaxf(acc[2] + ba.z, 0.f), fmaxf(acc[3] + ba.w, 0.f));
        o.z = pack2(fmaxf(acc[4] + bb.x, 0.f), fmaxf(acc[5] + bb.y, 0.f));
        o.w = pack2(fmaxf(acc[6] + bb.z, 0.f), fmaxf(acc[7] + bb.w, 0.f));
        reinterpret_cast<uint4*>(out)[(size_t)n * 32 + q] = o;
    }
}

// ---------------------------------------------------------------------------
// Pool stage 1: partial sums. Grid (G, 8 strides), block 128.
// ---------------------------------------------------------------------------
__device__ __forceinline__ int lower_bound_i(const int* a, int n, int val) {
    int lo = 0, hi = n;
    while (lo < hi) {
        int mid = (lo + hi) >> 1;
        if (a[mid] < val) lo = mid + 1; else hi = mid;
    }
    return lo;
}

__global__ __launch_bounds__(128) void k_pool_part(const unsigned* __restrict__ H,
                                                   const int* __restrict__ batch,
                                                   float* __restrict__ partial, int N) {
    const int g = blockIdx.x;
    const int s = blockIdx.y;
    const int p = threadIdx.x;
    const int lo = lower_bound_i(batch, N, g);
    const int hi = lower_bound_i(batch, N, g + 1);
    float sx = 0.f, sy = 0.f;
    for (int n = lo + s; n < hi; n += 8) {
        unsigned u = H[(size_t)n * 128 + p];
        sx += bf16lo(u);
        sy += bf16hi(u);
    }
    float2 v; v.x = sx; v.y = sy;
    reinterpret_cast<float2*>(partial)[(size_t)(g * 8 + s) * 128 + p] = v;
}

// ---------------------------------------------------------------------------
// Classifier (+ pool stage 2)
// ---------------------------------------------------------------------------
__global__ __launch_bounds__(256) void k_cls(const float* __restrict__ partial,
                                             const int* __restrict__ batch,
                                             const float* __restrict__ Wlin,
                                             const float* __restrict__ blin,
                                             float* __restrict__ out, int N) {
    __shared__ float part[NCLS][HIDDEN];
    const int g = blockIdx.x;
    const int t = threadIdx.x;
    const int lo = lower_bound_i(batch, N, g);
    const int hi = lower_bound_i(batch, N, g + 1);
    float p = 0.f;
#pragma unroll
    for (int s = 0; s < 8; ++s) p += partial[(size_t)(g * 8 + s) * HIDDEN + t];
    p /= fmaxf((float)(hi - lo), 1.f);
#pragma unroll
    for (int c = 0; c < NCLS; ++c) part[c][t] = p * Wlin[(size_t)t * NCLS + c];
    __syncthreads();
    for (int off = 128; off >= 1; off >>= 1) {
        if (t < off) {
#pragma unroll
            for (int c = 0; c < NCLS; ++c) part[c][t] += part[c][t + off];
        }
        __syncthreads();
    }
    if (t == 0) {
        float lg[NCLS];
        float m = -INFINITY;
#pragma unroll
        for (int c = 0; c < NCLS; ++c) {
            lg[c] = part[c][0] + blin[c];
            m = fmaxf(m, lg[c]);
        }
        float se = 0.f;
#pragma unroll
        for (int c = 0; c < NCLS; ++c) se += expf(lg[c] - m);
        float lse = m + logf(se);
#pragma unroll
        for (int c = 0; c < NCLS; ++c) out[(size_t)g * NCLS + c] = lg[c] - lse;
    }
}

// ---------------------------------------------------------------------------

extern "C" void kernel_launch(void* const* d_in, const int* in_sizes, int n_in,
                              void* d_out, int out_size, void* d_ws, size_t ws_size,
                              hipStream_t stream) {
    const float* x    = (const float*)d_in[0];
    const float* W1   = (const float*)d_in[1];
    const float* b1   = (const float*)d_in[2];
    const float* W2   = (const float*)d_in[3];
    const float* b2   = (const float*)d_in[4];
    const float* W3   = (const float*)d_in[5];
    const float* b3   = (const float*)d_in[6];
    const float* Wlin = (const float*)d_in[7];
    const float* blin = (const float*)d_in[8];
    const int*   eidx = (const int*)d_in[9];
    const int*   batch= (const int*)d_in[10];
    float* out = (float*)d_out;

    const int N = in_sizes[0] / HIDDEN;      // 10000
    const int E = in_sizes[9] / 2;           // 320000
    const int G = out_size / NCLS;           // 64
    const int Mp = (N + 63) & ~63;           // 10048

    const int* src = eidx;
    const int* dst = eidx + E;

    char* base = (char*)d_ws;
    size_t off = 0;
    auto alloc = [&](size_t bytes) -> void* {
        void* p = base + off;
        off = (off + bytes + 255) & ~(size_t)255;
        return p;
    };
    int*      ecnt     = (int*)     alloc((size_t)N * sizeof(int));
    int*      cursor   = (int*)     alloc((size_t)N * sizeof(int));
    float*    dinv     = (float*)   alloc((size_t)N * sizeof(float));
    int*      rowstart = (int*)     alloc((size_t)(N + 1) * sizeof(int));
    uint2*    csr      = (uint2*)   alloc((size_t)(E + 32) * sizeof(uint2)); // +32 pad (speculative desc loads)
    unsigned* x16      = (unsigned*)alloc((size_t)Mp * 128 * sizeof(unsigned));
    unsigned* hA       = (unsigned*)alloc((size_t)Mp * 128 * sizeof(unsigned));
    unsigned* hB       = (unsigned*)alloc((size_t)Mp * 128 * sizeof(unsigned));
    short8*   Wp1      = (short8*)  alloc((size_t)8192 * sizeof(short8));
    short8*   Wp2      = (short8*)  alloc((size_t)8192 * sizeof(short8));
    short8*   Wp3      = (short8*)  alloc((size_t)8192 * sizeof(short8));
    float*    partial  = (float*)   alloc((size_t)G * 8 * HIDDEN * sizeof(float));
    (void)ws_size;

    // --- preprocessing (k_zero kernel, NOT hipMemsetAsync: blit fill measured
    //     at ~42us/replay inside the captured graph) ---
    const int nbCount = (E + 255) / 256;          // 1250
    const int n4 = N * HIDDEN / 4;
    const int nb_cvt = (n4 + 255) / 256;          // 2500
    k_zero<<<(N + 255) / 256, 256, 0, stream>>>(ecnt, N);
    k_count_prep<<<nbCount + nb_cvt + 96, 256, 0, stream>>>(
        dst, ecnt, E, x, x16, W1, W2, W3, Wp1, Wp2, Wp3, n4, nbCount, nb_cvt);
    k_scan<<<1, 1024, 0, stream>>>(ecnt, rowstart, cursor, dinv, N, E);

    // --- CSR fill + layer-1 GEMM (merged) ---
    const int nbFill = (E + 255) / 256;           // 1250
    const int gemmBlocks = (Mp / 64) * 4;         // 628
    k_fill_gemm1<<<nbFill + gemmBlocks, 256, 0, stream>>>(
        src, dst, dinv, cursor, csr, E,
        (const unsigned short*)x16, Wp1, (unsigned short*)hA, nbFill);

    const dim3 ggrid(Mp / 64, 4);
    const int agg_blocks = (N + 3) / 4;
    // --- layer 1 agg ---
    k_agg <<<agg_blocks, 256, 0, stream>>>(hA, csr, rowstart, dinv, b1, hB, N);
    // --- layer 2 ---
    k_gemm<<<ggrid, 256, 0, stream>>>((const unsigned short*)hB, Wp2, (unsigned short*)hA);
    k_agg <<<agg_blocks, 256, 0, stream>>>(hA, csr, rowstart, dinv, b2, hB, N);
    // --- layer 3 ---
    k_gemm<<<ggrid, 256, 0, stream>>>((const unsigned short*)hB, Wp3, (unsigned short*)hA);
    k_agg <<<agg_blocks, 256, 0, stream>>>(hA, csr, rowstart, dinv, b3, hB, N);
    // --- pool (2-stage, deterministic) + classifier ---
    k_pool_part<<<dim3(G, 8), 128, 0, stream>>>(hB, batch, partial, N);
    k_cls <<<G, 256, 0, stream>>>(partial, batch, Wlin, blin, out, N);
}

// Round 12
// 170.236 us; speedup vs baseline: 1.2009x; 1.0273x over previous
//
#include <hip/hip_runtime.h>
#include <hip/hip_bf16.h>
#include <math.h>

#define HIDDEN 256
#define NCLS 10

typedef __attribute__((ext_vector_type(8))) short short8;
typedef __attribute__((ext_vector_type(4))) float f32x4;

// ---- bf16 helpers (bit-level, RTNE) ---------------------------------------
static __device__ __forceinline__ float bf16lo(unsigned u) {
    return __uint_as_float(u << 16);
}
static __device__ __forceinline__ float bf16hi(unsigned u) {
    return __uint_as_float(u & 0xffff0000u);
}
static __device__ __forceinline__ unsigned short f2bf(float f) {
    unsigned x = __float_as_uint(f);
    x += 0x7fffu + ((x >> 16) & 1u);       // round-to-nearest-even
    return (unsigned short)(x >> 16);
}
static __device__ __forceinline__ unsigned pack2(float lo, float hi) {
    return (unsigned)f2bf(lo) | ((unsigned)f2bf(hi) << 16);
}

static __device__ __forceinline__ void fma8(float* acc, uint4 u, float w) {
    acc[0] = fmaf(bf16lo(u.x), w, acc[0]);
    acc[1] = fmaf(bf16hi(u.x), w, acc[1]);
    acc[2] = fmaf(bf16lo(u.y), w, acc[2]);
    acc[3] = fmaf(bf16hi(u.y), w, acc[3]);
    acc[4] = fmaf(bf16lo(u.z), w, acc[4]);
    acc[5] = fmaf(bf16hi(u.z), w, acc[5]);
    acc[6] = fmaf(bf16lo(u.w), w, acc[6]);
    acc[7] = fmaf(bf16hi(u.w), w, acc[7]);
}

// ---------------------------------------------------------------------------
// Merged: in-degree count (blocks [0,nbCount)) + dtype prep (rest).
// Prep: x f32->bf16 (flat [Mp][256]), W1/W2/W3 -> MFMA B-fragments
//   frag id = (s*16 + t)*64 + lane ; elems j: W[32s + 8*(l>>4)+j][16t + (l&15)]
// ---------------------------------------------------------------------------
__global__ __launch_bounds__(256) void k_count_prep(const int* __restrict__ dst,
                                                    int* __restrict__ ecnt, int E,
                                                    const float* __restrict__ x,
                                                    unsigned* __restrict__ x16,
                                                    const float* __restrict__ W1,
                                                    const float* __restrict__ W2,
                                                    const float* __restrict__ W3,
                                                    short8* __restrict__ P1,
                                                    short8* __restrict__ P2,
                                                    short8* __restrict__ P3,
                                                    int n4, int nbCount, int nb_cvt) {
    const int b = blockIdx.x;
    if (b < nbCount) {
        int e = b * 256 + threadIdx.x;
        if (e < E) atomicAdd(&ecnt[dst[e]], 1);
    } else if (b < nbCount + nb_cvt) {
        int i = (b - nbCount) * 256 + threadIdx.x;
        if (i < n4) {
            float4 v = reinterpret_cast<const float4*>(x)[i];
            uint2 o;
            o.x = pack2(v.x, v.y);
            o.y = pack2(v.z, v.w);
            reinterpret_cast<uint2*>(x16)[i] = o;
        }
    } else {
        int pb = b - nbCount - nb_cvt;            // 0..95
        int which = pb >> 5;
        int id = (pb & 31) * 256 + threadIdx.x;   // 0..8191
        const float* W = (which == 0) ? W1 : (which == 1) ? W2 : W3;
        short8* P = (which == 0) ? P1 : (which == 1) ? P2 : P3;
        int l = id & 63;
        int tt = (id >> 6) & 15;
        int s = id >> 10;
        int col = tt * 16 + (l & 15);
        int k0 = s * 32 + (l >> 4) * 8;
        short8 v;
#pragma unroll
        for (int j = 0; j < 8; ++j)
            v[j] = (short)f2bf(W[(size_t)(k0 + j) * HIDDEN + col]);
        P[id] = v;
    }
}

// single-block scan; also emits cursor (=rowstart) and dinv
__global__ __launch_bounds__(1024) void k_scan(const int* __restrict__ ecnt,
                                               int* __restrict__ rowstart,
                                               int* __restrict__ cursor,
                                               float* __restrict__ dinv, int N, int E) {
    __shared__ int sums[1024];
    int t = threadIdx.x;
    const int CH = (N + 1023) / 1024;
    int base = t * CH;
    int local = 0;
    for (int i = 0; i < CH; ++i) {
        int idx = base + i;
        if (idx < N) local += ecnt[idx];
    }
    sums[t] = local;
    __syncthreads();
    for (int off = 1; off < 1024; off <<= 1) {
        int v = (t >= off) ? sums[t - off] : 0;
        __syncthreads();
        sums[t] += v;
        __syncthreads();
    }
    int run = (t == 0) ? 0 : sums[t - 1];
    for (int i = 0; i < CH; ++i) {
        int idx = base + i;
        if (idx < N) {
            rowstart[idx] = run;
            cursor[idx] = run;
            dinv[idx] = rsqrtf((float)(ecnt[idx] + 1));   // +1 self loop
            run += ecnt[idx];
        }
    }
    if (t == 0) rowstart[N] = E;
}

// ---------------------------------------------------------------------------
// GEMM body: C[Mp,256] = A[Mp,256] @ W (pre-packed fragments).
// Wave w: rows bx*64 + 16w, cols by*64 (4 n-frags). K fully unrolled.
// ---------------------------------------------------------------------------
static __device__ __forceinline__ void gemm_body(const unsigned short* __restrict__ A,
                                                 const short8* __restrict__ P,
                                                 unsigned short* __restrict__ C,
                                                 int bx, int by, int tid) {
    const int l = tid & 63;
    const int w = tid >> 6;
    const int g = l >> 4;
    const int r = l & 15;
    const int mwave = bx * 64 + w * 16;
    const int nb = by * 4;

    f32x4 acc[4] = {};
    const unsigned short* arow = A + (size_t)(mwave + r) * HIDDEN;

#pragma unroll
    for (int s = 0; s < 8; ++s) {
        short8 a = *reinterpret_cast<const short8*>(arow + s * 32 + g * 8);
#pragma unroll
        for (int f = 0; f < 4; ++f) {
            short8 bfrag = P[(s * 16 + nb + f) * 64 + l];
            acc[f] = __builtin_amdgcn_mfma_f32_16x16x32_bf16(a, bfrag, acc[f], 0, 0, 0);
        }
    }
#pragma unroll
    for (int f = 0; f < 4; ++f) {
        int col = by * 64 + f * 16 + r;
#pragma unroll
        for (int q = 0; q < 4; ++q) {
            int row = mwave + g * 4 + q;
            C[(size_t)row * HIDDEN + col] = f2bf(acc[f][q]);
        }
    }
}

__global__ __launch_bounds__(256) void k_gemm(const unsigned short* __restrict__ A,
                                              const short8* __restrict__ P,
                                              unsigned short* __restrict__ C) {
    gemm_body(A, P, C, blockIdx.x, blockIdx.y, threadIdx.x);
}

// ---------------------------------------------------------------------------
// Merged: CSR fill (blocks [0,nbFill)) + layer-1 GEMM (rest).
// ---------------------------------------------------------------------------
__global__ __launch_bounds__(256) void k_fill_gemm1(const int* __restrict__ src,
                                                    const int* __restrict__ dst,
                                                    const float* __restrict__ dinv,
                                                    int* __restrict__ cursor,
                                                    uint2* __restrict__ csr, int E,
                                                    const unsigned short* __restrict__ A,
                                                    const short8* __restrict__ P,
                                                    unsigned short* __restrict__ C,
                                                    int nbFill) {
    const int b = blockIdx.x;
    if (b < nbFill) {
        int e = b * 256 + threadIdx.x;
        if (e < E) {
            int d = dst[e];
            int s = src[e];
            int pos = atomicAdd(&cursor[d], 1);
            uint2 ent;
            ent.x = (unsigned)s;
            ent.y = __float_as_uint(dinv[s] * dinv[d]);
            csr[pos] = ent;
        }
    } else {
        int gb = b - nbFill;            // flattened as (bx<<2)|by
        gemm_body(A, P, C, gb >> 2, gb & 3, threadIdx.x);
    }
}

// ---------------------------------------------------------------------------
// Aggregation, channel-half phased, r7 instruction profile preserved.
// Grid ((N+3)/4, 2): y = channel half (x-fastest dispatch -> y=0's 2.57MB of
// H cache lines resident in per-XCD L2 before y=1 starts).
// Block = 4 waves = 4 nodes (on one half). Lane: q=l&15 = 16B chunk of the
// 256B half-row; s=l>>4 = edge substream (4 streams, 2-unroll each -> 8
// edges/iter, nfull≈4 at mean degree 32 — same pipeline depth as r7).
// 2-stage pipeline: fma iter i || row-gathers i+1 || descriptors i+2.
// csr padded +32 so speculative descriptor loads are safe.
// ---------------------------------------------------------------------------
__global__ __launch_bounds__(256) void k_agg(const unsigned* __restrict__ H,
                                             const uint2* __restrict__ csr,
                                             const int* __restrict__ rowstart,
                                             const float* __restrict__ dinv,
                                             const float* __restrict__ bias,
                                             unsigned* __restrict__ out, int N) {
    const int n = blockIdx.x * 4 + (threadIdx.x >> 6);
    if (n >= N) return;
    const int y = blockIdx.y;
    const int l = threadIdx.x & 63;
    const int s = l >> 4;                  // edge substream 0..3
    const int q = l & 15;                  // 16B chunk within half-row
    const int hoff = y * 16 + q;           // uint4 index within row
    const uint4* __restrict__ H4 = reinterpret_cast<const uint4*>(H);

    float acc[8] = {0.f, 0.f, 0.f, 0.f, 0.f, 0.f, 0.f, 0.f};
    if (s == 0) {
        const float di = dinv[n];
        fma8(acc, H4[(size_t)n * 32 + hoff], di * di);
    }

    const int base = rowstart[n];
    const int e1   = rowstart[n + 1];
    const int nfull = (e1 - base) >> 3;          // iterations of 8 edges
    const unsigned long long* cp =
        reinterpret_cast<const unsigned long long*>(csr) + base + 2 * s;

    if (nfull > 0) {
        // prologue: iter0 descriptors + rows, iter1 descriptors
        unsigned long long dA0 = cp[0];
        unsigned long long dA1 = cp[1];
        uint4 rA0 = H4[(size_t)(unsigned)dA0 * 32 + hoff];
        uint4 rA1 = H4[(size_t)(unsigned)dA1 * 32 + hoff];
        unsigned long long dB0 = cp[8];
        unsigned long long dB1 = cp[9];
        for (int it = 0; it + 1 < nfull; ++it) {
            cp += 8;
            uint4 rB0 = H4[(size_t)(unsigned)dB0 * 32 + hoff];   // rows iter it+1
            uint4 rB1 = H4[(size_t)(unsigned)dB1 * 32 + hoff];
            unsigned long long dC0 = cp[8];                      // descs iter it+2
            unsigned long long dC1 = cp[9];
            fma8(acc, rA0, __uint_as_float((unsigned)(dA0 >> 32)));
            fma8(acc, rA1, __uint_as_float((unsigned)(dA1 >> 32)));
            dA0 = dB0; dA1 = dB1;
            dB0 = dC0; dB1 = dC1;
            rA0 = rB0; rA1 = rB1;
        }
        fma8(acc, rA0, __uint_as_float((unsigned)(dA0 >> 32)));
        fma8(acc, rA1, __uint_as_float((unsigned)(dA1 >> 32)));
    }
    // tail: < 8 remaining edges, substreams take every 4th
    for (int e = base + 8 * nfull + s; e < e1; e += 4) {
        uint2 ed = csr[e];
        fma8(acc, H4[(size_t)ed.x * 32 + hoff], __uint_as_float(ed.y));
    }

    // reduce across the 4 substreams (lane bits 4 and 5)
#pragma unroll
    for (int j = 0; j < 8; ++j) {
        acc[j] += __shfl_xor(acc[j], 16);
        acc[j] += __shfl_xor(acc[j], 32);
    }

    if (s == 0) {
        const float4* __restrict__ b4 = reinterpret_cast<const float4*>(bias);
        float4 ba = b4[hoff * 2];
        float4 bb = b4[hoff * 2 + 1];
        uint4 o;
        o.x = pack2(fmaxf(acc[0] + ba.x, 0.f), fmaxf(acc[1] + ba.y, 0.f));
        o.y = pack2(fmaxf(acc[2] + ba.z, 0.f), fmaxf(acc[3] + ba.w, 0.f));
        o.z = pack2(fmaxf(acc[4] + bb.x, 0.f), fmaxf(acc[5] + bb.y, 0.f));
        o.w = pack2(fmaxf(acc[6] + bb.z, 0.f), fmaxf(acc[7] + bb.w, 0.f));
        reinterpret_cast<uint4*>(out)[(size_t)n * 32 + hoff] = o;
    }
}

// ---------------------------------------------------------------------------
// Pool stage 1: partial sums. Grid (G, 8 strides), block 128.
// ---------------------------------------------------------------------------
__device__ __forceinline__ int lower_bound_i(const int* a, int n, int val) {
    int lo = 0, hi = n;
    while (lo < hi) {
        int mid = (lo + hi) >> 1;
        if (a[mid] < val) lo = mid + 1; else hi = mid;
    }
    return lo;
}

__global__ __launch_bounds__(128) void k_pool_part(const unsigned* __restrict__ H,
                                                   const int* __restrict__ batch,
                                                   float* __restrict__ partial, int N) {
    const int g = blockIdx.x;
    const int s = blockIdx.y;
    const int p = threadIdx.x;
    const int lo = lower_bound_i(batch, N, g);
    const int hi = lower_bound_i(batch, N, g + 1);
    float sx = 0.f, sy = 0.f;
    for (int n = lo + s; n < hi; n += 8) {
        unsigned u = H[(size_t)n * 128 + p];
        sx += bf16lo(u);
        sy += bf16hi(u);
    }
    float2 v; v.x = sx; v.y = sy;
    reinterpret_cast<float2*>(partial)[(size_t)(g * 8 + s) * 128 + p] = v;
}

// ---------------------------------------------------------------------------
// Classifier (+ pool stage 2)
// ---------------------------------------------------------------------------
__global__ __launch_bounds__(256) void k_cls(const float* __restrict__ partial,
                                             const int* __restrict__ batch,
                                             const float* __restrict__ Wlin,
                                             const float* __restrict__ blin,
                                             float* __restrict__ out, int N) {
    __shared__ float part[NCLS][HIDDEN];
    const int g = blockIdx.x;
    const int t = threadIdx.x;
    const int lo = lower_bound_i(batch, N, g);
    const int hi = lower_bound_i(batch, N, g + 1);
    float p = 0.f;
#pragma unroll
    for (int s = 0; s < 8; ++s) p += partial[(size_t)(g * 8 + s) * HIDDEN + t];
    p /= fmaxf((float)(hi - lo), 1.f);
#pragma unroll
    for (int c = 0; c < NCLS; ++c) part[c][t] = p * Wlin[(size_t)t * NCLS + c];
    __syncthreads();
    for (int off = 128; off >= 1; off >>= 1) {
        if (t < off) {
#pragma unroll
            for (int c = 0; c < NCLS; ++c) part[c][t] += part[c][t + off];
        }
        __syncthreads();
    }
    if (t == 0) {
        float lg[NCLS];
        float m = -INFINITY;
#pragma unroll
        for (int c = 0; c < NCLS; ++c) {
            lg[c] = part[c][0] + blin[c];
            m = fmaxf(m, lg[c]);
        }
        float se = 0.f;
#pragma unroll
        for (int c = 0; c < NCLS; ++c) se += expf(lg[c] - m);
        float lse = m + logf(se);
#pragma unroll
        for (int c = 0; c < NCLS; ++c) out[(size_t)g * NCLS + c] = lg[c] - lse;
    }
}

// ---------------------------------------------------------------------------

extern "C" void kernel_launch(void* const* d_in, const int* in_sizes, int n_in,
                              void* d_out, int out_size, void* d_ws, size_t ws_size,
                              hipStream_t stream) {
    const float* x    = (const float*)d_in[0];
    const float* W1   = (const float*)d_in[1];
    const float* b1   = (const float*)d_in[2];
    const float* W2   = (const float*)d_in[3];
    const float* b2   = (const float*)d_in[4];
    const float* W3   = (const float*)d_in[5];
    const float* b3   = (const float*)d_in[6];
    const float* Wlin = (const float*)d_in[7];
    const float* blin = (const float*)d_in[8];
    const int*   eidx = (const int*)d_in[9];
    const int*   batch= (const int*)d_in[10];
    float* out = (float*)d_out;

    const int N = in_sizes[0] / HIDDEN;      // 10000
    const int E = in_sizes[9] / 2;           // 320000
    const int G = out_size / NCLS;           // 64
    const int Mp = (N + 63) & ~63;           // 10048

    const int* src = eidx;
    const int* dst = eidx + E;

    char* base = (char*)d_ws;
    size_t off = 0;
    auto alloc = [&](size_t bytes) -> void* {
        void* p = base + off;
        off = (off + bytes + 255) & ~(size_t)255;
        return p;
    };
    int*      ecnt     = (int*)     alloc((size_t)N * sizeof(int));
    int*      cursor   = (int*)     alloc((size_t)N * sizeof(int));
    float*    dinv     = (float*)   alloc((size_t)N * sizeof(float));
    int*      rowstart = (int*)     alloc((size_t)(N + 1) * sizeof(int));
    uint2*    csr      = (uint2*)   alloc((size_t)(E + 32) * sizeof(uint2)); // +32 pad (speculative desc loads)
    unsigned* x16      = (unsigned*)alloc((size_t)Mp * 128 * sizeof(unsigned));
    unsigned* hA       = (unsigned*)alloc((size_t)Mp * 128 * sizeof(unsigned));
    unsigned* hB       = (unsigned*)alloc((size_t)Mp * 128 * sizeof(unsigned));
    short8*   Wp1      = (short8*)  alloc((size_t)8192 * sizeof(short8));
    short8*   Wp2      = (short8*)  alloc((size_t)8192 * sizeof(short8));
    short8*   Wp3      = (short8*)  alloc((size_t)8192 * sizeof(short8));
    float*    partial  = (float*)   alloc((size_t)G * 8 * HIDDEN * sizeof(float));
    (void)ws_size;

    // --- preprocessing ---
    const int nbCount = (E + 255) / 256;          // 1250
    const int n4 = N * HIDDEN / 4;
    const int nb_cvt = (n4 + 255) / 256;          // 2500
    (void)hipMemsetAsync(ecnt, 0, (size_t)N * sizeof(int), stream);
    k_count_prep<<<nbCount + nb_cvt + 96, 256, 0, stream>>>(
        dst, ecnt, E, x, x16, W1, W2, W3, Wp1, Wp2, Wp3, n4, nbCount, nb_cvt);
    k_scan<<<1, 1024, 0, stream>>>(ecnt, rowstart, cursor, dinv, N, E);

    // --- CSR fill + layer-1 GEMM (merged) ---
    const int nbFill = (E + 255) / 256;           // 1250
    const int gemmBlocks = (Mp / 64) * 4;         // 628
    k_fill_gemm1<<<nbFill + gemmBlocks, 256, 0, stream>>>(
        src, dst, dinv, cursor, csr, E,
        (const unsigned short*)x16, Wp1, (unsigned short*)hA, nbFill);

    const dim3 ggrid(Mp / 64, 4);
    const dim3 agrid((N + 3) / 4, 2);
    // --- layer 1 agg ---
    k_agg <<<agrid, 256, 0, stream>>>(hA, csr, rowstart, dinv, b1, hB, N);
    // --- layer 2 ---
    k_gemm<<<ggrid, 256, 0, stream>>>((const unsigned short*)hB, Wp2, (unsigned short*)hA);
    k_agg <<<agrid, 256, 0, stream>>>(hA, csr, rowstart, dinv, b2, hB, N);
    // --- layer 3 ---
    k_gemm<<<ggrid, 256, 0, stream>>>((const unsigned short*)hB, Wp3, (unsigned short*)hA);
    k_agg <<<agrid, 256, 0, stream>>>(hA, csr, rowstart, dinv, b3, hB, N);
    // --- pool (2-stage, deterministic) + classifier ---
    k_pool_part<<<dim3(G, 8), 128, 0, stream>>>(hB, batch, partial, N);
    k_cls <<<G, 256, 0, stream>>>(partial, batch, Wlin, blin, out, N);
}

// Round 13
// 165.622 us; speedup vs baseline: 1.2343x; 1.0279x over previous
//
#include <hip/hip_runtime.h>
#include <hip/hip_bf16.h>
#include <math.h>

#define HIDDEN 256
#define NCLS 10

typedef __attribute__((ext_vector_type(8))) short short8;
typedef __attribute__((ext_vector_type(4))) float f32x4;

// ---- bf16 helpers (bit-level, RTNE) ---------------------------------------
static __device__ __forceinline__ float bf16lo(unsigned u) {
    return __uint_as_float((u & 0xffffu) << 16);
}
static __device__ __forceinline__ float bf16hi(unsigned u) {
    return __uint_as_float(u & 0xffff0000u);
}
static __device__ __forceinline__ unsigned short f2bf(float f) {
    unsigned x = __float_as_uint(f);
    x += 0x7fffu + ((x >> 16) & 1u);       // round-to-nearest-even
    return (unsigned short)(x >> 16);
}
static __device__ __forceinline__ unsigned pack2(float lo, float hi) {
    return (unsigned)f2bf(lo) | ((unsigned)f2bf(hi) << 16);
}

static __device__ __forceinline__ void fma8(float* acc, uint4 u, float w) {
    acc[0] = fmaf(bf16lo(u.x), w, acc[0]);
    acc[1] = fmaf(bf16hi(u.x), w, acc[1]);
    acc[2] = fmaf(bf16lo(u.y), w, acc[2]);
    acc[3] = fmaf(bf16hi(u.y), w, acc[3]);
    acc[4] = fmaf(bf16lo(u.z), w, acc[4]);
    acc[5] = fmaf(bf16hi(u.z), w, acc[5]);
    acc[6] = fmaf(bf16lo(u.w), w, acc[6]);
    acc[7] = fmaf(bf16hi(u.w), w, acc[7]);
}

// ---------------------------------------------------------------------------
// Merged: in-degree count (blocks [0,nbCount)) + dtype prep (rest).
// Prep: x f32->bf16, W1/W2/W3 -> MFMA B-fragments
//   frag id = (s*16 + t)*64 + lane ; elems j: W[32s + 8*(l>>4)+j][16t + (l&15)]
// ---------------------------------------------------------------------------
__global__ __launch_bounds__(256) void k_count_prep(const int* __restrict__ dst,
                                                    int* __restrict__ ecnt, int E,
                                                    const float* __restrict__ x,
                                                    unsigned* __restrict__ x16,
                                                    const float* __restrict__ W1,
                                                    const float* __restrict__ W2,
                                                    const float* __restrict__ W3,
                                                    short8* __restrict__ P1,
                                                    short8* __restrict__ P2,
                                                    short8* __restrict__ P3,
                                                    int n4, int nbCount, int nb_cvt) {
    const int b = blockIdx.x;
    if (b < nbCount) {
        int e = b * 256 + threadIdx.x;
        if (e < E) atomicAdd(&ecnt[dst[e]], 1);
    } else if (b < nbCount + nb_cvt) {
        int i = (b - nbCount) * 256 + threadIdx.x;
        if (i < n4) {
            float4 v = reinterpret_cast<const float4*>(x)[i];
            uint2 o;
            o.x = pack2(v.x, v.y);
            o.y = pack2(v.z, v.w);
            reinterpret_cast<uint2*>(x16)[i] = o;
        }
    } else {
        int pb = b - nbCount - nb_cvt;            // 0..95
        int which = pb >> 5;
        int id = (pb & 31) * 256 + threadIdx.x;   // 0..8191
        const float* W = (which == 0) ? W1 : (which == 1) ? W2 : W3;
        short8* P = (which == 0) ? P1 : (which == 1) ? P2 : P3;
        int l = id & 63;
        int tt = (id >> 6) & 15;
        int s = id >> 10;
        int col = tt * 16 + (l & 15);
        int k0 = s * 32 + (l >> 4) * 8;
        short8 v;
#pragma unroll
        for (int j = 0; j < 8; ++j)
            v[j] = (short)f2bf(W[(size_t)(k0 + j) * HIDDEN + col]);
        P[id] = v;
    }
}

// single-block scan; also emits cursor (=rowstart) and dinv
__global__ __launch_bounds__(1024) void k_scan(const int* __restrict__ ecnt,
                                               int* __restrict__ rowstart,
                                               int* __restrict__ cursor,
                                               float* __restrict__ dinv, int N, int E) {
    __shared__ int sums[1024];
    int t = threadIdx.x;
    const int CH = (N + 1023) / 1024;
    int base = t * CH;
    int local = 0;
    for (int i = 0; i < CH; ++i) {
        int idx = base + i;
        if (idx < N) local += ecnt[idx];
    }
    sums[t] = local;
    __syncthreads();
    for (int off = 1; off < 1024; off <<= 1) {
        int v = (t >= off) ? sums[t - off] : 0;
        __syncthreads();
        sums[t] += v;
        __syncthreads();
    }
    int run = (t == 0) ? 0 : sums[t - 1];
    for (int i = 0; i < CH; ++i) {
        int idx = base + i;
        if (idx < N) {
            rowstart[idx] = run;
            cursor[idx] = run;
            dinv[idx] = rsqrtf((float)(ecnt[idx] + 1));   // +1 self loop
            run += ecnt[idx];
        }
    }
    if (t == 0) rowstart[N] = E;
}

// ---------------------------------------------------------------------------
// GEMM body: C[Mp,256] = A[Mp,256] @ W (pre-packed fragments).
// Wave w: rows bx*64 + 16w, cols by*64 (4 n-frags). K fully unrolled.
// k-permutation-safe: A and B fragments use the same k formula.
// ---------------------------------------------------------------------------
static __device__ __forceinline__ void gemm_body(const unsigned short* __restrict__ A,
                                                 const short8* __restrict__ P,
                                                 unsigned short* __restrict__ C,
                                                 int bx, int by, int tid) {
    const int l = tid & 63;
    const int w = tid >> 6;
    const int g = l >> 4;
    const int r = l & 15;
    const int mwave = bx * 64 + w * 16;
    const int nb = by * 4;

    f32x4 acc[4] = {};
    const unsigned short* arow = A + (size_t)(mwave + r) * HIDDEN;

#pragma unroll
    for (int s = 0; s < 8; ++s) {
        short8 a = *reinterpret_cast<const short8*>(arow + s * 32 + g * 8);
#pragma unroll
        for (int f = 0; f < 4; ++f) {
            short8 bfrag = P[(s * 16 + nb + f) * 64 + l];
            acc[f] = __builtin_amdgcn_mfma_f32_16x16x32_bf16(a, bfrag, acc[f], 0, 0, 0);
        }
    }
#pragma unroll
    for (int f = 0; f < 4; ++f) {
        int col = by * 64 + f * 16 + r;
#pragma unroll
        for (int q = 0; q < 4; ++q) {
            int row = mwave + g * 4 + q;
            C[(size_t)row * HIDDEN + col] = f2bf(acc[f][q]);
        }
    }
}

__global__ __launch_bounds__(256) void k_gemm(const unsigned short* __restrict__ A,
                                              const short8* __restrict__ P,
                                              unsigned short* __restrict__ C) {
    gemm_body(A, P, C, blockIdx.x, blockIdx.y, threadIdx.x);
}

// ---------------------------------------------------------------------------
// Merged: CSR fill (blocks [0,nbFill)) + layer-1 GEMM (rest).
// agg1 depends on BOTH outputs, so merging is safe (no intra-kernel deps).
// ---------------------------------------------------------------------------
__global__ __launch_bounds__(256) void k_fill_gemm1(const int* __restrict__ src,
                                                    const int* __restrict__ dst,
                                                    const float* __restrict__ dinv,
                                                    int* __restrict__ cursor,
                                                    uint2* __restrict__ csr, int E,
                                                    const unsigned short* __restrict__ A,
                                                    const short8* __restrict__ P,
                                                    unsigned short* __restrict__ C,
                                                    int nbFill) {
    const int b = blockIdx.x;
    if (b < nbFill) {
        int e = b * 256 + threadIdx.x;
        if (e < E) {
            int d = dst[e];
            int s = src[e];
            int pos = atomicAdd(&cursor[d], 1);
            uint2 ent;
            ent.x = (unsigned)s;
            ent.y = __float_as_uint(dinv[s] * dinv[d]);
            csr[pos] = ent;
        }
    } else {
        int gb = b - nbFill;            // 0..627 ; flattened as (bx<<2)|by
        gemm_body(A, P, C, gb >> 2, gb & 3, threadIdx.x);
    }
}

// ---------------------------------------------------------------------------
// Aggregation (bf16 H): out[n] = relu( sum_e H[src]*w + H[n]*dinv^2 + b )
// Block = 4 waves = 4 nodes. Lane: chunk q=l&31 (8 ch, uint4), half h=l>>5.
// 2-stage software pipeline: while fma-ing iter i, iter i+1's row gathers and
// iter i+2's descriptors are in flight (csr padded +16 so speculative
// descriptor loads are safe; never dereferenced when past row end).
// ---------------------------------------------------------------------------
__global__ __launch_bounds__(256) void k_agg(const unsigned* __restrict__ H,
                                             const uint2* __restrict__ csr,
                                             const int* __restrict__ rowstart,
                                             const float* __restrict__ dinv,
                                             const float* __restrict__ bias,
                                             unsigned* __restrict__ out, int N) {
    const int n = blockIdx.x * 4 + (threadIdx.x >> 6);
    if (n >= N) return;
    const int l = threadIdx.x & 63;
    const int q = l & 31;
    const int h = l >> 5;
    const uint4* __restrict__ H4 = reinterpret_cast<const uint4*>(H);

    float acc[8] = {0.f, 0.f, 0.f, 0.f, 0.f, 0.f, 0.f, 0.f};
    if (h == 0) {
        const float di = dinv[n];
        fma8(acc, H4[(size_t)n * 32 + q], di * di);
    }

    const int base = rowstart[n];
    const int e1   = rowstart[n + 1];
    const int nfull = (e1 - base) >> 3;          // iterations of 8 edges
    const uint2* cp = csr + base + 4 * h;        // this half's stream (stride 8)

    if (nfull > 0) {
        // prologue: iter0 descriptors + rows, iter1 descriptors
        uint2 dA0 = cp[0], dA1 = cp[1], dA2 = cp[2], dA3 = cp[3];
        uint4 rA0 = H4[(size_t)dA0.x * 32 + q];
        uint4 rA1 = H4[(size_t)dA1.x * 32 + q];
        uint4 rA2 = H4[(size_t)dA2.x * 32 + q];
        uint4 rA3 = H4[(size_t)dA3.x * 32 + q];
        uint2 dB0 = cp[8], dB1 = cp[9], dB2 = cp[10], dB3 = cp[11];
        for (int it = 0; it + 1 < nfull; ++it) {
            cp += 8;
            uint4 rB0 = H4[(size_t)dB0.x * 32 + q];   // rows for iter it+1
            uint4 rB1 = H4[(size_t)dB1.x * 32 + q];
            uint4 rB2 = H4[(size_t)dB2.x * 32 + q];
            uint4 rB3 = H4[(size_t)dB3.x * 32 + q];
            uint2 dC0 = cp[8], dC1 = cp[9], dC2 = cp[10], dC3 = cp[11]; // iter it+2
            fma8(acc, rA0, __uint_as_float(dA0.y));   // consume iter it
            fma8(acc, rA1, __uint_as_float(dA1.y));
            fma8(acc, rA2, __uint_as_float(dA2.y));
            fma8(acc, rA3, __uint_as_float(dA3.y));
            dA0 = dB0; dA1 = dB1; dA2 = dB2; dA3 = dB3;
            dB0 = dC0; dB1 = dC1; dB2 = dC2; dB3 = dC3;
            rA0 = rB0; rA1 = rB1; rA2 = rB2; rA3 = rB3;
        }
        fma8(acc, rA0, __uint_as_float(dA0.y));       // last full iter
        fma8(acc, rA1, __uint_as_float(dA1.y));
        fma8(acc, rA2, __uint_as_float(dA2.y));
        fma8(acc, rA3, __uint_as_float(dA3.y));
    }
    // tail: < 8 remaining edges, split by half (stride 2)
    for (int e = base + 8 * nfull + h; e < e1; e += 2) {
        uint2 ed = csr[e];
        fma8(acc, H4[(size_t)ed.x * 32 + q], __uint_as_float(ed.y));
    }

#pragma unroll
    for (int j = 0; j < 8; ++j) acc[j] += __shfl_xor(acc[j], 32);

    if (h == 0) {
        const float4* __restrict__ b4 = reinterpret_cast<const float4*>(bias);
        float4 ba = b4[q * 2];
        float4 bb = b4[q * 2 + 1];
        uint4 o;
        o.x = pack2(fmaxf(acc[0] + ba.x, 0.f), fmaxf(acc[1] + ba.y, 0.f));
        o.y = pack2(fmaxf(acc[2] + ba.z, 0.f), fmaxf(acc[3] + ba.w, 0.f));
        o.z = pack2(fmaxf(acc[4] + bb.x, 0.f), fmaxf(acc[5] + bb.y, 0.f));
        o.w = pack2(fmaxf(acc[6] + bb.z, 0.f), fmaxf(acc[7] + bb.w, 0.f));
        reinterpret_cast<uint4*>(out)[(size_t)n * 32 + q] = o;
    }
}

// ---------------------------------------------------------------------------
// Pool stage 1: partial sums. Grid (G, 8 strides), block 128.
// ---------------------------------------------------------------------------
__device__ __forceinline__ int lower_bound_i(const int* a, int n, int val) {
    int lo = 0, hi = n;
    while (lo < hi) {
        int mid = (lo + hi) >> 1;
        if (a[mid] < val) lo = mid + 1; else hi = mid;
    }
    return lo;
}

__global__ __launch_bounds__(128) void k_pool_part(const unsigned* __restrict__ H,
                                                   const int* __restrict__ batch,
                                                   float* __restrict__ partial, int N) {
    const int g = blockIdx.x;
    const int s = blockIdx.y;
    const int p = threadIdx.x;
    const int lo = lower_bound_i(batch, N, g);
    const int hi = lower_bound_i(batch, N, g + 1);
    float sx = 0.f, sy = 0.f;
    for (int n = lo + s; n < hi; n += 8) {
        unsigned u = H[(size_t)n * 128 + p];
        sx += bf16lo(u);
        sy += bf16hi(u);
    }
    float2 v; v.x = sx; v.y = sy;
    reinterpret_cast<float2*>(partial)[(size_t)(g * 8 + s) * 128 + p] = v;
}

// ---------------------------------------------------------------------------
// Classifier (+ pool stage 2)
// ---------------------------------------------------------------------------
__global__ __launch_bounds__(256) void k_cls(const float* __restrict__ partial,
                                             const int* __restrict__ batch,
                                             const float* __restrict__ Wlin,
                                             const float* __restrict__ blin,
                                             float* __restrict__ out, int N) {
    __shared__ float part[NCLS][HIDDEN];
    const int g = blockIdx.x;
    const int t = threadIdx.x;
    const int lo = lower_bound_i(batch, N, g);
    const int hi = lower_bound_i(batch, N, g + 1);
    float p = 0.f;
#pragma unroll
    for (int s = 0; s < 8; ++s) p += partial[(size_t)(g * 8 + s) * HIDDEN + t];
    p /= fmaxf((float)(hi - lo), 1.f);
#pragma unroll
    for (int c = 0; c < NCLS; ++c) part[c][t] = p * Wlin[(size_t)t * NCLS + c];
    __syncthreads();
    for (int off = 128; off >= 1; off >>= 1) {
        if (t < off) {
#pragma unroll
            for (int c = 0; c < NCLS; ++c) part[c][t] += part[c][t + off];
        }
        __syncthreads();
    }
    if (t == 0) {
        float lg[NCLS];
        float m = -INFINITY;
#pragma unroll
        for (int c = 0; c < NCLS; ++c) {
            lg[c] = part[c][0] + blin[c];
            m = fmaxf(m, lg[c]);
        }
        float se = 0.f;
#pragma unroll
        for (int c = 0; c < NCLS; ++c) se += expf(lg[c] - m);
        float lse = m + logf(se);
#pragma unroll
        for (int c = 0; c < NCLS; ++c) out[(size_t)g * NCLS + c] = lg[c] - lse;
    }
}

// ---------------------------------------------------------------------------

extern "C" void kernel_launch(void* const* d_in, const int* in_sizes, int n_in,
                              void* d_out, int out_size, void* d_ws, size_t ws_size,
                              hipStream_t stream) {
    const float* x    = (const float*)d_in[0];
    const float* W1   = (const float*)d_in[1];
    const float* b1   = (const float*)d_in[2];
    const float* W2   = (const float*)d_in[3];
    const float* b2   = (const float*)d_in[4];
    const float* W3   = (const float*)d_in[5];
    const float* b3   = (const float*)d_in[6];
    const float* Wlin = (const float*)d_in[7];
    const float* blin = (const float*)d_in[8];
    const int*   eidx = (const int*)d_in[9];
    const int*   batch= (const int*)d_in[10];
    float* out = (float*)d_out;

    const int N = in_sizes[0] / HIDDEN;      // 10000
    const int E = in_sizes[9] / 2;           // 320000
    const int G = out_size / NCLS;           // 64
    const int Mp = (N + 63) & ~63;           // 10048

    const int* src = eidx;
    const int* dst = eidx + E;

    char* base = (char*)d_ws;
    size_t off = 0;
    auto alloc = [&](size_t bytes) -> void* {
        void* p = base + off;
        off = (off + bytes + 255) & ~(size_t)255;
        return p;
    };
    int*      ecnt     = (int*)     alloc((size_t)N * sizeof(int));
    int*      cursor   = (int*)     alloc((size_t)N * sizeof(int));
    float*    dinv     = (float*)   alloc((size_t)N * sizeof(float));
    int*      rowstart = (int*)     alloc((size_t)(N + 1) * sizeof(int));
    uint2*    csr      = (uint2*)   alloc((size_t)(E + 16) * sizeof(uint2)); // +16 pad for speculative loads
    unsigned* x16      = (unsigned*)alloc((size_t)Mp * 128 * sizeof(unsigned));
    unsigned* hA       = (unsigned*)alloc((size_t)Mp * 128 * sizeof(unsigned));
    unsigned* hB       = (unsigned*)alloc((size_t)Mp * 128 * sizeof(unsigned));
    short8*   Wp1      = (short8*)  alloc((size_t)8192 * sizeof(short8));
    short8*   Wp2      = (short8*)  alloc((size_t)8192 * sizeof(short8));
    short8*   Wp3      = (short8*)  alloc((size_t)8192 * sizeof(short8));
    float*    partial  = (float*)   alloc((size_t)G * 8 * HIDDEN * sizeof(float));
    (void)ws_size;

    // --- preprocessing (discrete launches; no grid.sync) ---
    const int nbCount = (E + 255) / 256;          // 1250
    const int n4 = N * HIDDEN / 4;
    const int nb_cvt = (n4 + 255) / 256;          // 2500
    (void)hipMemsetAsync(ecnt, 0, (size_t)N * sizeof(int), stream);
    k_count_prep<<<nbCount + nb_cvt + 96, 256, 0, stream>>>(
        dst, ecnt, E, x, x16, W1, W2, W3, Wp1, Wp2, Wp3, n4, nbCount, nb_cvt);
    k_scan<<<1, 1024, 0, stream>>>(ecnt, rowstart, cursor, dinv, N, E);

    // --- CSR fill + layer-1 GEMM (merged) ---
    const int nbFill = (E + 255) / 256;           // 1250
    const int gemmBlocks = (Mp / 64) * 4;         // 628
    k_fill_gemm1<<<nbFill + gemmBlocks, 256, 0, stream>>>(
        src, dst, dinv, cursor, csr, E,
        (const unsigned short*)x16, Wp1, (unsigned short*)hA, nbFill);

    const dim3 ggrid(Mp / 64, 4);
    const int agg_blocks = (N + 3) / 4;
    // --- layer 1 agg ---
    k_agg <<<agg_blocks, 256, 0, stream>>>(hA, csr, rowstart, dinv, b1, hB, N);
    // --- layer 2 ---
    k_gemm<<<ggrid, 256, 0, stream>>>((const unsigned short*)hB, Wp2, (unsigned short*)hA);
    k_agg <<<agg_blocks, 256, 0, stream>>>(hA, csr, rowstart, dinv, b2, hB, N);
    // --- layer 3 ---
    k_gemm<<<ggrid, 256, 0, stream>>>((const unsigned short*)hB, Wp3, (unsigned short*)hA);
    k_agg <<<agg_blocks, 256, 0, stream>>>(hA, csr, rowstart, dinv, b3, hB, N);
    // --- pool (2-stage, deterministic) + classifier ---
    k_pool_part<<<dim3(G, 8), 128, 0, stream>>>(hB, batch, partial, N);
    k_cls <<<G, 256, 0, stream>>>(partial, batch, Wlin, blin, out, N);
}